// Round 1
// baseline (434.365 us; speedup 1.0000x reference)
//
#include <hip/hip_runtime.h>
#include <hip/hip_bf16.h>

// ---------------- constants ----------------
#define B_SZ 2
#define L_SZ 512
#define D_MODEL 512
#define D_INNER 1024
#define HEAD_DIM 64
#define NHEADS 16
#define D_STATE 64
#define D_CONV 3
#define CONV_DIM 1152            // D_INNER + 2*D_STATE
#define D_IN_PROJ 2192           // 2*D_INNER + 2*D_STATE + NHEADS
#define BL (B_SZ * L_SZ)         // 1024
#define RMS_EPS 1e-5f
#define NCHUNK 4                 // n-split of the scan (D_STATE/16)

// ---------------- generic fp32 tiled GEMM: C[M,N] = A[M,K] * B[K,N] ----------------
__global__ __launch_bounds__(256) void gemm_tiled(const float* __restrict__ A,
                                                  const float* __restrict__ Bm,
                                                  float* __restrict__ C,
                                                  int M, int N, int K) {
    __shared__ float As[16][65];   // [k][m], padded pitch to avoid write conflicts
    __shared__ float Bs[16][64];   // [k][n]
    int tid = threadIdx.x;
    int m0 = blockIdx.y * 64, n0 = blockIdx.x * 64;
    int tx = tid & 15, ty = tid >> 4;

    int la_m = tid >> 2;           // 0..63
    int la_k = (tid & 3) * 4;      // 0,4,8,12
    int lb_k = tid >> 4;           // 0..15
    int lb_n = (tid & 15) * 4;     // 0..60

    float acc[4][4] = {{0.f}};

    for (int k0 = 0; k0 < K; k0 += 16) {
        float4 av = *(const float4*)(A + (size_t)(m0 + la_m) * K + k0 + la_k);
        float4 bv = make_float4(0.f, 0.f, 0.f, 0.f);
        if (n0 + lb_n < N)
            bv = *(const float4*)(Bm + (size_t)(k0 + lb_k) * N + n0 + lb_n);
        __syncthreads();           // protect previous iteration's reads
        As[la_k + 0][la_m] = av.x;
        As[la_k + 1][la_m] = av.y;
        As[la_k + 2][la_m] = av.z;
        As[la_k + 3][la_m] = av.w;
        *(float4*)&Bs[lb_k][lb_n] = bv;
        __syncthreads();
#pragma unroll
        for (int kk = 0; kk < 16; ++kk) {
            float a_[4], b_[4];
#pragma unroll
            for (int i = 0; i < 4; ++i) a_[i] = As[kk][ty * 4 + i];
#pragma unroll
            for (int j = 0; j < 4; ++j) b_[j] = Bs[kk][tx * 4 + j];
#pragma unroll
            for (int i = 0; i < 4; ++i)
#pragma unroll
                for (int j = 0; j < 4; ++j)
                    acc[i][j] += a_[i] * b_[j];
        }
    }
#pragma unroll
    for (int i = 0; i < 4; ++i) {
        int row = m0 + ty * 4 + i;
        int col = n0 + tx * 4;
        if (col < N) {
            float4 o = make_float4(acc[i][0], acc[i][1], acc[i][2], acc[i][3]);
            *(float4*)(C + (size_t)row * N + col) = o;
        }
    }
}

// ---------------- causal depthwise conv (k=3) + bias + SiLU ----------------
// in: zxbcdt cols [1024, 2176)  -> out: xBC [BL, 1152]
__global__ __launch_bounds__(256) void conv_silu_kernel(const float* __restrict__ zxbcdt,
                                                        const float* __restrict__ conv_w,
                                                        const float* __restrict__ conv_b,
                                                        float* __restrict__ xBC) {
    int bl = blockIdx.x;             // b*512 + l
    int l = bl & (L_SZ - 1);
    const float* base = zxbcdt + (size_t)bl * D_IN_PROJ + D_INNER;
    for (int c = threadIdx.x; c < CONV_DIM; c += blockDim.x) {
        float w0 = conv_w[c * 3 + 0], w1 = conv_w[c * 3 + 1], w2 = conv_w[c * 3 + 2];
        float acc = conv_b[c] + w2 * base[c];
        if (l >= 1) acc += w1 * base[c - D_IN_PROJ];
        if (l >= 2) acc += w0 * base[c - 2 * D_IN_PROJ];
        float s = acc / (1.f + expf(-acc));   // SiLU
        xBC[(size_t)bl * CONV_DIM + c] = s;
    }
}

// ---------------- SSM sequential scan (chunk=1 SSD == recurrence) ----------------
// 128 blocks: (b, h, n-chunk). 256 threads: p = tid>>2 (0..63), sub = tid&3 (4 states each).
__global__ __launch_bounds__(256) void ssm_scan_kernel(const float* __restrict__ zxbcdt,
                                                       const float* __restrict__ xBC,
                                                       const float* __restrict__ dt_bias,
                                                       const float* __restrict__ A_log,
                                                       float* __restrict__ y_part) {
    int blk = blockIdx.x;          // 0..127
    int chunk = blk & 3;
    int h = (blk >> 2) & 15;
    int b = blk >> 6;
    int tid = threadIdx.x;
    int p = tid >> 2;
    int sub = tid & 3;
    int nb = chunk * 16 + sub * 4;

    float A = -expf(A_log[h]);
    float dtb = dt_bias[h];

    const float* xbase = xBC + (size_t)b * L_SZ * CONV_DIM;
    const float* dtbase = zxbcdt + (size_t)b * L_SZ * D_IN_PROJ + 2 * D_INNER + 2 * D_STATE + h;
    float* ybase = y_part + (size_t)chunk * BL * D_INNER + (size_t)b * L_SZ * D_INNER + h * 64 + p;

    float s0 = 0.f, s1 = 0.f, s2 = 0.f, s3 = 0.f;

    // prefetch t=0
    float xv = xbase[h * 64 + p];
    float4 Bv = *(const float4*)(xbase + D_INNER + nb);
    float4 Cv = *(const float4*)(xbase + D_INNER + D_STATE + nb);
    float dtraw = *dtbase;

    for (int t = 0; t < L_SZ; ++t) {
        float xn = 0.f, dtn = 0.f;
        float4 Bn = make_float4(0, 0, 0, 0), Cn = make_float4(0, 0, 0, 0);
        if (t + 1 < L_SZ) {
            const float* nx = xbase + (size_t)(t + 1) * CONV_DIM;
            xn = nx[h * 64 + p];
            Bn = *(const float4*)(nx + D_INNER + nb);
            Cn = *(const float4*)(nx + D_INNER + D_STATE + nb);
            dtn = dtbase[(size_t)(t + 1) * D_IN_PROJ];
        }
        float dtv = dtraw + dtb;
        dtv = (dtv > 20.f) ? dtv : log1pf(expf(dtv));   // softplus
        float a = expf(A * dtv);
        float dtx = dtv * xv;
        s0 = a * s0 + dtx * Bv.x;
        s1 = a * s1 + dtx * Bv.y;
        s2 = a * s2 + dtx * Bv.z;
        s3 = a * s3 + dtx * Bv.w;
        float accv = Cv.x * s0 + Cv.y * s1 + Cv.z * s2 + Cv.w * s3;
        accv += __shfl_xor(accv, 1);
        accv += __shfl_xor(accv, 2);
        if (sub == 0) ybase[(size_t)t * D_INNER] = accv;
        xv = xn; Bv = Bn; Cv = Cn; dtraw = dtn;
    }
}

// ---------------- y-combine + D*x + gate (SiLU(z)) + RMSNorm ----------------
__global__ __launch_bounds__(256) void gated_rmsnorm_kernel(const float* __restrict__ zxbcdt,
                                                            const float* __restrict__ xBC,
                                                            const float* __restrict__ y_part,
                                                            const float* __restrict__ D_param,
                                                            const float* __restrict__ rms_w,
                                                            float* __restrict__ yn) {
    int bl = blockIdx.x;   // 0..1023
    int tid = threadIdx.x;
    __shared__ float red[4];
    __shared__ float sscale;
    float vals[4];
    float sumsq = 0.f;
#pragma unroll
    for (int i = 0; i < 4; ++i) {
        int col = tid + i * 256;
        int h = col >> 6;
        size_t o = (size_t)bl * D_INNER + col;
        float y = y_part[o] + y_part[o + (size_t)BL * D_INNER] +
                  y_part[o + 2 * (size_t)BL * D_INNER] + y_part[o + 3 * (size_t)BL * D_INNER];
        y += D_param[h] * xBC[(size_t)bl * CONV_DIM + col];
        float z = zxbcdt[(size_t)bl * D_IN_PROJ + col];
        float yz = y * (z / (1.f + expf(-z)));
        vals[i] = yz;
        sumsq += yz * yz;
    }
#pragma unroll
    for (int off = 32; off; off >>= 1) sumsq += __shfl_xor(sumsq, off);
    int wave = tid >> 6, lane = tid & 63;
    if (lane == 0) red[wave] = sumsq;
    __syncthreads();
    if (tid == 0) {
        float t = red[0] + red[1] + red[2] + red[3];
        sscale = rsqrtf(t / (float)D_INNER + RMS_EPS);
    }
    __syncthreads();
    float sc = sscale;
#pragma unroll
    for (int i = 0; i < 4; ++i) {
        int col = tid + i * 256;
        yn[(size_t)bl * D_INNER + col] = vals[i] * sc * rms_w[col];
    }
}

// ---------------- launch ----------------
extern "C" void kernel_launch(void* const* d_in, const int* in_sizes, int n_in,
                              void* d_out, int out_size, void* d_ws, size_t ws_size,
                              hipStream_t stream) {
    const float* u       = (const float*)d_in[0];
    const float* W_in    = (const float*)d_in[1];
    const float* conv_w  = (const float*)d_in[2];
    const float* conv_b  = (const float*)d_in[3];
    const float* dt_bias = (const float*)d_in[4];
    const float* A_log   = (const float*)d_in[5];
    const float* D_param = (const float*)d_in[6];
    const float* rms_w   = (const float*)d_in[7];
    const float* W_out   = (const float*)d_in[8];
    float* out = (float*)d_out;

    float* ws = (float*)d_ws;
    float* zxbcdt = ws;                                  // [1024, 2192]
    float* xBC    = zxbcdt + (size_t)BL * D_IN_PROJ;     // [1024, 1152]
    float* y_part = xBC + (size_t)BL * CONV_DIM;         // [4][1024][1024]
    float* yn     = y_part + (size_t)NCHUNK * BL * D_INNER; // [1024, 1024]

    // 1) in_proj GEMM: zxbcdt = u @ W_in   (1024 x 2192 x 512)
    gemm_tiled<<<dim3((D_IN_PROJ + 63) / 64, BL / 64), 256, 0, stream>>>(
        u, W_in, zxbcdt, BL, D_IN_PROJ, D_MODEL);

    // 2) causal dwconv + SiLU
    conv_silu_kernel<<<BL, 256, 0, stream>>>(zxbcdt, conv_w, conv_b, xBC);

    // 3) SSM scan (n split into 4 chunks)
    ssm_scan_kernel<<<B_SZ * NHEADS * NCHUNK, 256, 0, stream>>>(
        zxbcdt, xBC, dt_bias, A_log, y_part);

    // 4) combine + gate + RMSNorm
    gated_rmsnorm_kernel<<<BL, 256, 0, stream>>>(zxbcdt, xBC, y_part, D_param, rms_w, yn);

    // 5) out_proj GEMM: out = yn @ W_out   (1024 x 512 x 1024)
    gemm_tiled<<<dim3(D_MODEL / 64, BL / 64), 256, 0, stream>>>(
        yn, W_out, out, BL, D_MODEL, D_INNER);
}

// Round 2
// 157.973 us; speedup vs baseline: 2.7496x; 2.7496x over previous
//
#include <hip/hip_runtime.h>
#include <hip/hip_bf16.h>

// ---------------- constants ----------------
#define B_SZ 2
#define L_SZ 512
#define D_MODEL 512
#define D_INNER 1024
#define HEAD_DIM 64
#define NHEADS 16
#define D_STATE 64
#define D_CONV 3
#define CONV_DIM 1152            // D_INNER + 2*D_STATE
#define D_IN_PROJ 2192           // 2*D_INNER + 2*D_STATE + NHEADS
#define BL (B_SZ * L_SZ)         // 1024
#define RMS_EPS 1e-5f
#define QC 64                    // SSD chunk length
#define NCH 8                    // chunks per batch (L_SZ/QC)
#define LP 68                    // LDS row pitch (floats), 16B-aligned rows

// ---------------- generic fp32 tiled GEMM: C[M,N] = A[M,K] * B[K,N] ----------------
__global__ __launch_bounds__(256) void gemm_tiled(const float* __restrict__ A,
                                                  const float* __restrict__ Bm,
                                                  float* __restrict__ C,
                                                  int M, int N, int K) {
    __shared__ float As[16][65];
    __shared__ float Bs[16][64];
    int tid = threadIdx.x;
    int m0 = blockIdx.y * 64, n0 = blockIdx.x * 64;
    int tx = tid & 15, ty = tid >> 4;

    int la_m = tid >> 2;
    int la_k = (tid & 3) * 4;
    int lb_k = tid >> 4;
    int lb_n = (tid & 15) * 4;

    float acc[4][4] = {{0.f}};

    for (int k0 = 0; k0 < K; k0 += 16) {
        float4 av = *(const float4*)(A + (size_t)(m0 + la_m) * K + k0 + la_k);
        float4 bv = make_float4(0.f, 0.f, 0.f, 0.f);
        if (n0 + lb_n < N)
            bv = *(const float4*)(Bm + (size_t)(k0 + lb_k) * N + n0 + lb_n);
        __syncthreads();
        As[la_k + 0][la_m] = av.x;
        As[la_k + 1][la_m] = av.y;
        As[la_k + 2][la_m] = av.z;
        As[la_k + 3][la_m] = av.w;
        *(float4*)&Bs[lb_k][lb_n] = bv;
        __syncthreads();
#pragma unroll
        for (int kk = 0; kk < 16; ++kk) {
            float a_[4], b_[4];
#pragma unroll
            for (int i = 0; i < 4; ++i) a_[i] = As[kk][ty * 4 + i];
#pragma unroll
            for (int j = 0; j < 4; ++j) b_[j] = Bs[kk][tx * 4 + j];
#pragma unroll
            for (int i = 0; i < 4; ++i)
#pragma unroll
                for (int j = 0; j < 4; ++j)
                    acc[i][j] += a_[i] * b_[j];
        }
    }
#pragma unroll
    for (int i = 0; i < 4; ++i) {
        int row = m0 + ty * 4 + i;
        int col = n0 + tx * 4;
        if (col < N) {
            float4 o = make_float4(acc[i][0], acc[i][1], acc[i][2], acc[i][3]);
            *(float4*)(C + (size_t)row * N + col) = o;
        }
    }
}

// ---------------- causal depthwise conv (k=3) + bias + SiLU ----------------
__global__ __launch_bounds__(256) void conv_silu_kernel(const float* __restrict__ zxbcdt,
                                                        const float* __restrict__ conv_w,
                                                        const float* __restrict__ conv_b,
                                                        float* __restrict__ xBC) {
    int bl = blockIdx.x;
    int l = bl & (L_SZ - 1);
    const float* base = zxbcdt + (size_t)bl * D_IN_PROJ + D_INNER;
    for (int c = threadIdx.x; c < CONV_DIM; c += blockDim.x) {
        float w0 = conv_w[c * 3 + 0], w1 = conv_w[c * 3 + 1], w2 = conv_w[c * 3 + 2];
        float acc = conv_b[c] + w2 * base[c];
        if (l >= 1) acc += w1 * base[c - D_IN_PROJ];
        if (l >= 2) acc += w0 * base[c - 2 * D_IN_PROJ];
        float s = acc / (1.f + expf(-acc));
        xBC[(size_t)bl * CONV_DIM + c] = s;
    }
}

// ---------------- SSD pass A: per (b,c,h) chunk: Y_diag + D*x, chunk state Z, decays E ----------------
// block = 256 threads; Y_diag = (C B^T ∘ L) XD ; Z[p][n] = sum_t w_t XD[t,p] B[t,n]
__global__ __launch_bounds__(256) void ssd_passA(const float* __restrict__ zxbcdt,
                                                 const float* __restrict__ xBC,
                                                 const float* __restrict__ dt_bias,
                                                 const float* __restrict__ A_log,
                                                 const float* __restrict__ D_param,
                                                 float* __restrict__ y,
                                                 float* __restrict__ Zbuf,
                                                 float* __restrict__ Ebuf) {
    int blk = blockIdx.x;          // b*128 + c*16 + h
    int h = blk & 15;
    int c = (blk >> 4) & 7;
    int b = blk >> 7;
    int tid = threadIdx.x;

    __shared__ float Bs[QC][LP], Cs[QC][LP], XDs[QC][LP], Ps[QC][LP];
    __shared__ float csh[QC], dts[QC], wh[QC];

    int bl0 = b * L_SZ + c * QC;

    // dt, cumsum (wave 0, lanes = t)
    if (tid < 64) {
        int t = tid;
        float draw = zxbcdt[(size_t)(bl0 + t) * D_IN_PROJ + 2 * D_INNER + 2 * D_STATE + h];
        float dtv = draw + dt_bias[h];
        dtv = (dtv > 20.f) ? dtv : log1pf(expf(dtv));
        float A = -expf(A_log[h]);
        float a = A * dtv;
        float cs = a;
#pragma unroll
        for (int off = 1; off < 64; off <<= 1) {
            float tmp = __shfl_up(cs, off);
            if (t >= off) cs += tmp;
        }
        float cs63 = __shfl(cs, 63);
        dts[t] = dtv;
        csh[t] = cs;
        wh[t] = __expf(cs63 - cs);
        Ebuf[(((size_t)(b * NHEADS + h) * NCH) + c) * QC + t] = __expf(cs);
    }

    int row16 = tid >> 4;          // 0..15
    int col4 = (tid & 15) * 4;     // 0..60
#pragma unroll
    for (int r = 0; r < 4; ++r) {
        int t = r * 16 + row16;
        const float* xrow = xBC + (size_t)(bl0 + t) * CONV_DIM;
        *(float4*)&Bs[t][col4] = *(const float4*)(xrow + D_INNER + col4);
        *(float4*)&Cs[t][col4] = *(const float4*)(xrow + D_INNER + D_STATE + col4);
    }
    __syncthreads();               // dts + B/C visible
#pragma unroll
    for (int r = 0; r < 4; ++r) {
        int t = r * 16 + row16;
        const float* xrow = xBC + (size_t)(bl0 + t) * CONV_DIM + h * HEAD_DIM;
        float4 xv = *(const float4*)(xrow + col4);
        float d = dts[t];
        xv.x *= d; xv.y *= d; xv.z *= d; xv.w *= d;
        *(float4*)&XDs[t][col4] = xv;
    }
    __syncthreads();

    int tx = tid & 15, ty = tid >> 4;
    int t0 = ty * 4, s0 = tx * 4;

    // G = C B^T  (rows t, cols s), then mask+decay -> Ps
    {
        float g[4][4] = {{0.f}};
#pragma unroll
        for (int n4 = 0; n4 < 16; ++n4) {
            float4 ca[4], cb[4];
#pragma unroll
            for (int i = 0; i < 4; ++i) ca[i] = *(float4*)&Cs[t0 + i][n4 * 4];
#pragma unroll
            for (int j = 0; j < 4; ++j) cb[j] = *(float4*)&Bs[s0 + j][n4 * 4];
#pragma unroll
            for (int i = 0; i < 4; ++i)
#pragma unroll
                for (int j = 0; j < 4; ++j)
                    g[i][j] += ca[i].x * cb[j].x + ca[i].y * cb[j].y +
                               ca[i].z * cb[j].z + ca[i].w * cb[j].w;
        }
#pragma unroll
        for (int i = 0; i < 4; ++i) {
            int t = t0 + i; float cst = csh[t];
#pragma unroll
            for (int j = 0; j < 4; ++j) {
                int s = s0 + j;
                Ps[t][s] = (s <= t) ? g[i][j] * __expf(cst - csh[s]) : 0.f;
            }
        }
    }
    __syncthreads();

    // Y_diag = P @ XD  (rows t, cols p);  y = Y_diag + D*x
    {
        int p0 = tx * 4;
        float yv[4][4] = {{0.f}};
#pragma unroll
        for (int s4 = 0; s4 < 16; ++s4) {
            float4 pa[4], xb[4];
#pragma unroll
            for (int i = 0; i < 4; ++i) pa[i] = *(float4*)&Ps[t0 + i][s4 * 4];
#pragma unroll
            for (int k = 0; k < 4; ++k) xb[k] = *(float4*)&XDs[s4 * 4 + k][p0];
#pragma unroll
            for (int i = 0; i < 4; ++i) {
                float pav[4] = {pa[i].x, pa[i].y, pa[i].z, pa[i].w};
#pragma unroll
                for (int k = 0; k < 4; ++k) {
                    yv[i][0] += pav[k] * xb[k].x;
                    yv[i][1] += pav[k] * xb[k].y;
                    yv[i][2] += pav[k] * xb[k].z;
                    yv[i][3] += pav[k] * xb[k].w;
                }
            }
        }
        float Dp = D_param[h];
#pragma unroll
        for (int i = 0; i < 4; ++i) {
            int t = t0 + i;
            const float* xrow = xBC + (size_t)(bl0 + t) * CONV_DIM + h * HEAD_DIM;
            float* yrow = y + (size_t)(bl0 + t) * D_INNER + h * HEAD_DIM;
            float4 xv = *(const float4*)(xrow + p0);
            float4 o = make_float4(yv[i][0] + Dp * xv.x, yv[i][1] + Dp * xv.y,
                                   yv[i][2] + Dp * xv.z, yv[i][3] + Dp * xv.w);
            *(float4*)(yrow + p0) = o;
        }
    }

    // Z[p][n] = sum_t XD[t][p] * (w_t * B[t][n])   (rows p = t0.., cols n = s0..)
    {
        float zv[4][4] = {{0.f}};
#pragma unroll
        for (int t4 = 0; t4 < 16; ++t4) {
            float4 xa[4], bb[4];
#pragma unroll
            for (int k = 0; k < 4; ++k) {
                int t = t4 * 4 + k;
                xa[k] = *(float4*)&XDs[t][t0];
                float4 bv = *(float4*)&Bs[t][s0];
                float wt = wh[t];
                bv.x *= wt; bv.y *= wt; bv.z *= wt; bv.w *= wt;
                bb[k] = bv;
            }
#pragma unroll
            for (int k = 0; k < 4; ++k) {
                float xav[4] = {xa[k].x, xa[k].y, xa[k].z, xa[k].w};
#pragma unroll
                for (int i = 0; i < 4; ++i) {
                    zv[i][0] += xav[i] * bb[k].x;
                    zv[i][1] += xav[i] * bb[k].y;
                    zv[i][2] += xav[i] * bb[k].z;
                    zv[i][3] += xav[i] * bb[k].w;
                }
            }
        }
        float* Zr = Zbuf + (((size_t)(b * NHEADS + h) * NCH) + c) * (HEAD_DIM * D_STATE);
#pragma unroll
        for (int i = 0; i < 4; ++i)
            *(float4*)(Zr + (t0 + i) * D_STATE + s0) =
                make_float4(zv[i][0], zv[i][1], zv[i][2], zv[i][3]);
    }
}

// ---------------- SSD pass B: inter-chunk state recurrence (per b,h) ----------------
__global__ __launch_bounds__(256) void ssd_passB(const float* __restrict__ Zbuf,
                                                 const float* __restrict__ Ebuf,
                                                 float* __restrict__ Sbuf) {
    int bh = blockIdx.x;           // 0..31
    int tid = threadIdx.x;
    const float* Zb = Zbuf + (size_t)bh * NCH * 4096;
    float* Sb = Sbuf + (size_t)bh * NCH * 4096;
    const float* Eb = Ebuf + (size_t)bh * NCH * QC;
    float4 S[4];
#pragma unroll
    for (int k = 0; k < 4; ++k) S[k] = make_float4(0.f, 0.f, 0.f, 0.f);
    for (int c = 0; c < NCH; ++c) {
#pragma unroll
        for (int k = 0; k < 4; ++k)
            *(float4*)(Sb + (size_t)c * 4096 + k * 1024 + tid * 4) = S[k];
        float dec = Eb[c * QC + 63];
#pragma unroll
        for (int k = 0; k < 4; ++k) {
            float4 z = *(const float4*)(Zb + (size_t)c * 4096 + k * 1024 + tid * 4);
            S[k].x = dec * S[k].x + z.x;
            S[k].y = dec * S[k].y + z.y;
            S[k].z = dec * S[k].z + z.z;
            S[k].w = dec * S[k].w + z.w;
        }
    }
}

// ---------------- SSD pass C: Y_off = E ∘ (C @ S_prev^T), accumulate into y ----------------
__global__ __launch_bounds__(256) void ssd_passC(const float* __restrict__ xBC,
                                                 const float* __restrict__ Sbuf,
                                                 const float* __restrict__ Ebuf,
                                                 float* __restrict__ y) {
    int blk = blockIdx.x;          // b*128 + c*16 + h
    int h = blk & 15;
    int c = (blk >> 4) & 7;
    int b = blk >> 7;
    int tid = threadIdx.x;
    __shared__ float Cs[QC][LP], Sp[HEAD_DIM][LP];
    __shared__ float Eh[QC];
    int bl0 = b * L_SZ + c * QC;
    int row16 = tid >> 4, col4 = (tid & 15) * 4;
    const float* Sr = Sbuf + (((size_t)(b * NHEADS + h) * NCH) + c) * 4096;
#pragma unroll
    for (int r = 0; r < 4; ++r) {
        int t = r * 16 + row16;
        *(float4*)&Cs[t][col4] =
            *(const float4*)(xBC + (size_t)(bl0 + t) * CONV_DIM + D_INNER + D_STATE + col4);
        *(float4*)&Sp[t][col4] = *(const float4*)(Sr + t * 64 + col4);
    }
    if (tid < 64)
        Eh[tid] = Ebuf[(((size_t)(b * NHEADS + h) * NCH) + c) * QC + tid];
    __syncthreads();

    int tx = tid & 15, ty = tid >> 4;
    int t0 = ty * 4, p0 = tx * 4;
    float acc[4][4] = {{0.f}};
#pragma unroll
    for (int n4 = 0; n4 < 16; ++n4) {
        float4 ca[4], sb[4];
#pragma unroll
        for (int i = 0; i < 4; ++i) ca[i] = *(float4*)&Cs[t0 + i][n4 * 4];
#pragma unroll
        for (int j = 0; j < 4; ++j) sb[j] = *(float4*)&Sp[p0 + j][n4 * 4];
#pragma unroll
        for (int i = 0; i < 4; ++i)
#pragma unroll
            for (int j = 0; j < 4; ++j)
                acc[i][j] += ca[i].x * sb[j].x + ca[i].y * sb[j].y +
                             ca[i].z * sb[j].z + ca[i].w * sb[j].w;
    }
#pragma unroll
    for (int i = 0; i < 4; ++i) {
        int t = t0 + i;
        float Et = Eh[t];
        float* yrow = y + (size_t)(bl0 + t) * D_INNER + h * HEAD_DIM;
        float4 old = *(float4*)(yrow + p0);
        old.x += Et * acc[i][0];
        old.y += Et * acc[i][1];
        old.z += Et * acc[i][2];
        old.w += Et * acc[i][3];
        *(float4*)(yrow + p0) = old;
    }
}

// ---------------- gate (SiLU(z)) + RMSNorm ----------------
__global__ __launch_bounds__(256) void gated_rmsnorm_kernel(const float* __restrict__ zxbcdt,
                                                            const float* __restrict__ y,
                                                            const float* __restrict__ rms_w,
                                                            float* __restrict__ yn) {
    int bl = blockIdx.x;
    int tid = threadIdx.x;
    __shared__ float red[4];
    __shared__ float sscale;
    float vals[4];
    float sumsq = 0.f;
#pragma unroll
    for (int i = 0; i < 4; ++i) {
        int col = tid + i * 256;
        float yv = y[(size_t)bl * D_INNER + col];
        float z = zxbcdt[(size_t)bl * D_IN_PROJ + col];
        float yz = yv * (z / (1.f + expf(-z)));
        vals[i] = yz;
        sumsq += yz * yz;
    }
#pragma unroll
    for (int off = 32; off; off >>= 1) sumsq += __shfl_xor(sumsq, off);
    int wave = tid >> 6, lane = tid & 63;
    if (lane == 0) red[wave] = sumsq;
    __syncthreads();
    if (tid == 0) {
        float t = red[0] + red[1] + red[2] + red[3];
        sscale = rsqrtf(t / (float)D_INNER + RMS_EPS);
    }
    __syncthreads();
    float sc = sscale;
#pragma unroll
    for (int i = 0; i < 4; ++i) {
        int col = tid + i * 256;
        yn[(size_t)bl * D_INNER + col] = vals[i] * sc * rms_w[col];
    }
}

// ---------------- launch ----------------
extern "C" void kernel_launch(void* const* d_in, const int* in_sizes, int n_in,
                              void* d_out, int out_size, void* d_ws, size_t ws_size,
                              hipStream_t stream) {
    const float* u       = (const float*)d_in[0];
    const float* W_in    = (const float*)d_in[1];
    const float* conv_w  = (const float*)d_in[2];
    const float* conv_b  = (const float*)d_in[3];
    const float* dt_bias = (const float*)d_in[4];
    const float* A_log   = (const float*)d_in[5];
    const float* D_param = (const float*)d_in[6];
    const float* rms_w   = (const float*)d_in[7];
    const float* W_out   = (const float*)d_in[8];
    float* out = (float*)d_out;

    float* ws = (float*)d_ws;
    float* zxbcdt = ws;                                    // [1024][2192]
    float* xBC    = zxbcdt + (size_t)BL * D_IN_PROJ;       // [1024][1152]
    float* y      = xBC + (size_t)BL * CONV_DIM;           // [1024][1024]
    float* yn     = y + (size_t)BL * D_INNER;              // [1024][1024]
    float* Zbuf   = yn + (size_t)BL * D_INNER;             // [32][8][64][64]
    float* Sbuf   = Zbuf + (size_t)32 * NCH * 4096;        // [32][8][64][64]
    float* Ebuf   = Sbuf + (size_t)32 * NCH * 4096;        // [32][8][64]

    gemm_tiled<<<dim3((D_IN_PROJ + 63) / 64, BL / 64), 256, 0, stream>>>(
        u, W_in, zxbcdt, BL, D_IN_PROJ, D_MODEL);

    conv_silu_kernel<<<BL, 256, 0, stream>>>(zxbcdt, conv_w, conv_b, xBC);

    ssd_passA<<<B_SZ * NCH * NHEADS, 256, 0, stream>>>(
        zxbcdt, xBC, dt_bias, A_log, D_param, y, Zbuf, Ebuf);

    ssd_passB<<<B_SZ * NHEADS, 256, 0, stream>>>(Zbuf, Ebuf, Sbuf);

    ssd_passC<<<B_SZ * NCH * NHEADS, 256, 0, stream>>>(xBC, Sbuf, Ebuf, y);

    gated_rmsnorm_kernel<<<BL, 256, 0, stream>>>(zxbcdt, y, rms_w, yn);

    gemm_tiled<<<dim3(D_MODEL / 64, BL / 64), 256, 0, stream>>>(
        yn, W_out, out, BL, D_MODEL, D_INNER);
}

// Round 3
// 87.093 us; speedup vs baseline: 4.9874x; 1.8138x over previous
//
#include <hip/hip_runtime.h>
#include <hip/hip_bf16.h>

// ---------------- constants ----------------
#define B_SZ 2
#define L_SZ 512
#define D_MODEL 512
#define D_INNER 1024
#define HEAD_DIM 64
#define NHEADS 16
#define D_STATE 64
#define D_CONV 3
#define CONV_DIM 1152            // D_INNER + 2*D_STATE
#define D_IN_PROJ 2192           // 2*D_INNER + 2*D_STATE + NHEADS
#define BL (B_SZ * L_SZ)         // 1024
#define RMS_EPS 1e-5f
#define QC 64                    // SSD chunk length
#define NCH 8                    // chunks per batch (L_SZ/QC)
#define LP 68                    // LDS row pitch (floats)
#define NPAD1 2304               // W_in^T padded rows (18*128)

typedef __attribute__((ext_vector_type(8))) short short8t;
typedef __attribute__((ext_vector_type(8))) unsigned short ushort8t;
typedef __attribute__((ext_vector_type(4))) float f32x4;

__device__ __forceinline__ unsigned short f2bf(float f) {
    unsigned u = __float_as_uint(f);
    u += 0x7fff + ((u >> 16) & 1);          // round-to-nearest-even
    return (unsigned short)(u >> 16);
}

__device__ __forceinline__ void gload_lds16(const void* g, void* lds) {
    __builtin_amdgcn_global_load_lds(
        (const __attribute__((address_space(1))) unsigned int*)g,
        (__attribute__((address_space(3))) unsigned int*)lds, 16, 0, 0);
}

// ---------------- prep: W_in -> Wt1[N=2304][K=512] bf16, W_out -> Wt2[512][1024] bf16, u -> bf16
__device__ __forceinline__ void transpose_tile_bf16(const float* __restrict__ src,
                                                    unsigned short* __restrict__ dst,
                                                    int K, int Nin, int tile, int ntn) {
    __shared__ float T[64][65];
    int tid = threadIdx.x;
    int nt = tile % ntn, kt = tile / ntn;
    int n0 = nt * 64, k0 = kt * 64;
#pragma unroll
    for (int rr = 0; rr < 4; ++rr) {
        int k = k0 + (tid >> 4) + rr * 16;
        int nn = (tid & 15) * 4;
#pragma unroll
        for (int q = 0; q < 4; ++q) {
            int n = n0 + nn + q;
            T[(tid >> 4) + rr * 16][nn + q] = (n < Nin) ? src[(size_t)k * Nin + n] : 0.f;
        }
    }
    __syncthreads();
    int nn2 = tid >> 2, kc = tid & 3;
    unsigned short ov[16];
#pragma unroll
    for (int j = 0; j < 16; ++j) ov[j] = f2bf(T[kc * 16 + j][nn2]);
    unsigned short* p = dst + (size_t)(n0 + nn2) * K + k0 + kc * 16;
    *(ushort8t*)p = *(ushort8t*)&ov[0];
    *(ushort8t*)(p + 8) = *(ushort8t*)&ov[8];
}

__global__ __launch_bounds__(256) void prep_kernel(const float* __restrict__ W_in,
                                                   const float* __restrict__ W_out,
                                                   const float* __restrict__ u,
                                                   unsigned short* __restrict__ Wt1,
                                                   unsigned short* __restrict__ Wt2,
                                                   unsigned short* __restrict__ u_bf) {
    int bid = blockIdx.x;
    if (bid < 288) {                    // W_in [512][2192] -> Wt1 [2304][512]
        transpose_tile_bf16(W_in, Wt1, D_MODEL, D_IN_PROJ, bid, 36);
    } else if (bid < 416) {             // W_out [1024][512] -> Wt2 [512][1024]
        transpose_tile_bf16(W_out, Wt2, D_INNER, D_MODEL, bid - 288, 8);
    } else {                            // u [1024*512] -> bf16
        int i = ((bid - 416) * 256 + threadIdx.x) * 8;
        float4 v0 = *(const float4*)(u + i);
        float4 v1 = *(const float4*)(u + i + 4);
        unsigned short ov[8] = {f2bf(v0.x), f2bf(v0.y), f2bf(v0.z), f2bf(v0.w),
                                f2bf(v1.x), f2bf(v1.y), f2bf(v1.z), f2bf(v1.w)};
        *(ushort8t*)(u_bf + i) = *(ushort8t*)&ov[0];
    }
}

// ---------------- bf16 MFMA GEMM: C[M,N] = A[M,K] * Bt[N,K]^T ----------------
// 128x128 tile, BK=32, 4 waves (2x2), each wave 64x64 (4x4 frags of 16x16x32).
__global__ __launch_bounds__(256) void gemm_mfma(const unsigned short* __restrict__ A,
                                                 const unsigned short* __restrict__ Bt,
                                                 float* __restrict__ C,
                                                 int N, int K) {
    __shared__ char sm[32768];          // [2][A:8192][B:8192]
    int tid = threadIdx.x;
    int w = tid >> 6, l = tid & 63;
    int m0 = blockIdx.y * 128, n0 = blockIdx.x * 128;
    int wm = w >> 1, wn = w & 1;

    f32x4 acc[4][4];
#pragma unroll
    for (int i = 0; i < 4; ++i)
#pragma unroll
        for (int j = 0; j < 4; ++j) acc[i][j] = (f32x4){0.f, 0.f, 0.f, 0.f};

    // stage one 128x32 bf16 tile (8KB) : 8 segments of 16 rows, wave w does segs 2w,2w+1
    auto stage = [&](const unsigned short* src, int row0, int k0, char* dst) {
#pragma unroll
        for (int i = 0; i < 2; ++i) {
            int s = w * 2 + i;
            int row = row0 + s * 16 + (l >> 2);
            gload_lds16(src + (size_t)row * K + k0 + (l & 3) * 8, dst + s * 1024);
        }
    };

    int nkt = K / 32;
    int cur = 0;
    stage(A, m0, 0, sm);
    stage(Bt, n0, 0, sm + 8192);
    __syncthreads();

    for (int kt = 0; kt < nkt; ++kt) {
        if (kt + 1 < nkt) {
            stage(A, m0, (kt + 1) * 32, sm + (cur ^ 1) * 16384);
            stage(Bt, n0, (kt + 1) * 32, sm + (cur ^ 1) * 16384 + 8192);
        }
        const char* Ab = sm + cur * 16384;
        const char* Bb = Ab + 8192;
        short8t af[4], bf[4];
#pragma unroll
        for (int i = 0; i < 4; ++i)
            af[i] = *(const short8t*)(Ab + (wm * 64 + i * 16 + (l & 15)) * 64 + (l >> 4) * 16);
#pragma unroll
        for (int j = 0; j < 4; ++j)
            bf[j] = *(const short8t*)(Bb + (wn * 64 + j * 16 + (l & 15)) * 64 + (l >> 4) * 16);
#pragma unroll
        for (int i = 0; i < 4; ++i)
#pragma unroll
            for (int j = 0; j < 4; ++j)
                acc[i][j] = __builtin_amdgcn_mfma_f32_16x16x32_bf16(af[i], bf[j], acc[i][j], 0, 0, 0);
        __syncthreads();
        cur ^= 1;
    }

#pragma unroll
    for (int i = 0; i < 4; ++i)
#pragma unroll
        for (int j = 0; j < 4; ++j) {
            int row = m0 + wm * 64 + i * 16 + (l >> 4) * 4;
            int col = n0 + wn * 64 + j * 16 + (l & 15);
            if (col < N) {
#pragma unroll
                for (int r = 0; r < 4; ++r)
                    C[(size_t)(row + r) * N + col] = acc[i][j][r];
            }
        }
}

// ---------------- causal depthwise conv (k=3) + bias + SiLU ----------------
__global__ __launch_bounds__(256) void conv_silu_kernel(const float* __restrict__ zxbcdt,
                                                        const float* __restrict__ conv_w,
                                                        const float* __restrict__ conv_b,
                                                        float* __restrict__ xBC) {
    int bl = blockIdx.x;
    int l = bl & (L_SZ - 1);
    const float* base = zxbcdt + (size_t)bl * D_IN_PROJ + D_INNER;
    for (int c = threadIdx.x; c < CONV_DIM; c += blockDim.x) {
        float w0 = conv_w[c * 3 + 0], w1 = conv_w[c * 3 + 1], w2 = conv_w[c * 3 + 2];
        float acc = conv_b[c] + w2 * base[c];
        if (l >= 1) acc += w1 * base[c - D_IN_PROJ];
        if (l >= 2) acc += w0 * base[c - 2 * D_IN_PROJ];
        float s = acc / (1.f + expf(-acc));
        xBC[(size_t)bl * CONV_DIM + c] = s;
    }
}

// ---------------- SSD pass A ----------------
__global__ __launch_bounds__(256) void ssd_passA(const float* __restrict__ zxbcdt,
                                                 const float* __restrict__ xBC,
                                                 const float* __restrict__ dt_bias,
                                                 const float* __restrict__ A_log,
                                                 const float* __restrict__ D_param,
                                                 float* __restrict__ y,
                                                 float* __restrict__ Zbuf,
                                                 float* __restrict__ Ebuf) {
    int blk = blockIdx.x;          // b*128 + c*16 + h
    int h = blk & 15;
    int c = (blk >> 4) & 7;
    int b = blk >> 7;
    int tid = threadIdx.x;

    __shared__ float Bs[QC][LP], Cs[QC][LP], XDs[QC][LP], Ps[QC][LP];
    __shared__ float csh[QC], dts[QC], wh[QC];

    int bl0 = b * L_SZ + c * QC;

    if (tid < 64) {
        int t = tid;
        float draw = zxbcdt[(size_t)(bl0 + t) * D_IN_PROJ + 2 * D_INNER + 2 * D_STATE + h];
        float dtv = draw + dt_bias[h];
        dtv = (dtv > 20.f) ? dtv : log1pf(expf(dtv));
        float A = -expf(A_log[h]);
        float a = A * dtv;
        float cs = a;
#pragma unroll
        for (int off = 1; off < 64; off <<= 1) {
            float tmp = __shfl_up(cs, off);
            if (t >= off) cs += tmp;
        }
        float cs63 = __shfl(cs, 63);
        dts[t] = dtv;
        csh[t] = cs;
        wh[t] = __expf(cs63 - cs);
        Ebuf[(((size_t)(b * NHEADS + h) * NCH) + c) * QC + t] = __expf(cs);
    }

    int row16 = tid >> 4;
    int col4 = (tid & 15) * 4;
#pragma unroll
    for (int r = 0; r < 4; ++r) {
        int t = r * 16 + row16;
        const float* xrow = xBC + (size_t)(bl0 + t) * CONV_DIM;
        *(float4*)&Bs[t][col4] = *(const float4*)(xrow + D_INNER + col4);
        *(float4*)&Cs[t][col4] = *(const float4*)(xrow + D_INNER + D_STATE + col4);
    }
    __syncthreads();
#pragma unroll
    for (int r = 0; r < 4; ++r) {
        int t = r * 16 + row16;
        const float* xrow = xBC + (size_t)(bl0 + t) * CONV_DIM + h * HEAD_DIM;
        float4 xv = *(const float4*)(xrow + col4);
        float d = dts[t];
        xv.x *= d; xv.y *= d; xv.z *= d; xv.w *= d;
        *(float4*)&XDs[t][col4] = xv;
    }
    __syncthreads();

    int tx = tid & 15, ty = tid >> 4;
    int t0 = ty * 4, s0 = tx * 4;

    {
        float g[4][4] = {{0.f}};
#pragma unroll
        for (int n4 = 0; n4 < 16; ++n4) {
            float4 ca[4], cb[4];
#pragma unroll
            for (int i = 0; i < 4; ++i) ca[i] = *(float4*)&Cs[t0 + i][n4 * 4];
#pragma unroll
            for (int j = 0; j < 4; ++j) cb[j] = *(float4*)&Bs[s0 + j][n4 * 4];
#pragma unroll
            for (int i = 0; i < 4; ++i)
#pragma unroll
                for (int j = 0; j < 4; ++j)
                    g[i][j] += ca[i].x * cb[j].x + ca[i].y * cb[j].y +
                               ca[i].z * cb[j].z + ca[i].w * cb[j].w;
        }
#pragma unroll
        for (int i = 0; i < 4; ++i) {
            int t = t0 + i; float cst = csh[t];
#pragma unroll
            for (int j = 0; j < 4; ++j) {
                int s = s0 + j;
                Ps[t][s] = (s <= t) ? g[i][j] * __expf(cst - csh[s]) : 0.f;
            }
        }
    }
    __syncthreads();

    {
        int p0 = tx * 4;
        float yv[4][4] = {{0.f}};
#pragma unroll
        for (int s4 = 0; s4 < 16; ++s4) {
            float4 pa[4], xb[4];
#pragma unroll
            for (int i = 0; i < 4; ++i) pa[i] = *(float4*)&Ps[t0 + i][s4 * 4];
#pragma unroll
            for (int k = 0; k < 4; ++k) xb[k] = *(float4*)&XDs[s4 * 4 + k][p0];
#pragma unroll
            for (int i = 0; i < 4; ++i) {
                float pav[4] = {pa[i].x, pa[i].y, pa[i].z, pa[i].w};
#pragma unroll
                for (int k = 0; k < 4; ++k) {
                    yv[i][0] += pav[k] * xb[k].x;
                    yv[i][1] += pav[k] * xb[k].y;
                    yv[i][2] += pav[k] * xb[k].z;
                    yv[i][3] += pav[k] * xb[k].w;
                }
            }
        }
        float Dp = D_param[h];
#pragma unroll
        for (int i = 0; i < 4; ++i) {
            int t = t0 + i;
            const float* xrow = xBC + (size_t)(bl0 + t) * CONV_DIM + h * HEAD_DIM;
            float* yrow = y + (size_t)(bl0 + t) * D_INNER + h * HEAD_DIM;
            float4 xv = *(const float4*)(xrow + p0);
            float4 o = make_float4(yv[i][0] + Dp * xv.x, yv[i][1] + Dp * xv.y,
                                   yv[i][2] + Dp * xv.z, yv[i][3] + Dp * xv.w);
            *(float4*)(yrow + p0) = o;
        }
    }

    {
        float zv[4][4] = {{0.f}};
#pragma unroll
        for (int t4 = 0; t4 < 16; ++t4) {
            float4 xa[4], bb[4];
#pragma unroll
            for (int k = 0; k < 4; ++k) {
                int t = t4 * 4 + k;
                xa[k] = *(float4*)&XDs[t][t0];
                float4 bv = *(float4*)&Bs[t][s0];
                float wt = wh[t];
                bv.x *= wt; bv.y *= wt; bv.z *= wt; bv.w *= wt;
                bb[k] = bv;
            }
#pragma unroll
            for (int k = 0; k < 4; ++k) {
                float xav[4] = {xa[k].x, xa[k].y, xa[k].z, xa[k].w};
#pragma unroll
                for (int i = 0; i < 4; ++i) {
                    zv[i][0] += xav[i] * bb[k].x;
                    zv[i][1] += xav[i] * bb[k].y;
                    zv[i][2] += xav[i] * bb[k].z;
                    zv[i][3] += xav[i] * bb[k].w;
                }
            }
        }
        float* Zr = Zbuf + (((size_t)(b * NHEADS + h) * NCH) + c) * (HEAD_DIM * D_STATE);
#pragma unroll
        for (int i = 0; i < 4; ++i)
            *(float4*)(Zr + (t0 + i) * D_STATE + s0) =
                make_float4(zv[i][0], zv[i][1], zv[i][2], zv[i][3]);
    }
}

// ---------------- SSD pass B ----------------
__global__ __launch_bounds__(256) void ssd_passB(const float* __restrict__ Zbuf,
                                                 const float* __restrict__ Ebuf,
                                                 float* __restrict__ Sbuf) {
    int bh = blockIdx.x;
    int tid = threadIdx.x;
    const float* Zb = Zbuf + (size_t)bh * NCH * 4096;
    float* Sb = Sbuf + (size_t)bh * NCH * 4096;
    const float* Eb = Ebuf + (size_t)bh * NCH * QC;
    float4 S[4];
#pragma unroll
    for (int k = 0; k < 4; ++k) S[k] = make_float4(0.f, 0.f, 0.f, 0.f);
    for (int c = 0; c < NCH; ++c) {
#pragma unroll
        for (int k = 0; k < 4; ++k)
            *(float4*)(Sb + (size_t)c * 4096 + k * 1024 + tid * 4) = S[k];
        float dec = Eb[c * QC + 63];
#pragma unroll
        for (int k = 0; k < 4; ++k) {
            float4 z = *(const float4*)(Zb + (size_t)c * 4096 + k * 1024 + tid * 4);
            S[k].x = dec * S[k].x + z.x;
            S[k].y = dec * S[k].y + z.y;
            S[k].z = dec * S[k].z + z.z;
            S[k].w = dec * S[k].w + z.w;
        }
    }
}

// ---------------- SSD pass C ----------------
__global__ __launch_bounds__(256) void ssd_passC(const float* __restrict__ xBC,
                                                 const float* __restrict__ Sbuf,
                                                 const float* __restrict__ Ebuf,
                                                 float* __restrict__ y) {
    int blk = blockIdx.x;
    int h = blk & 15;
    int c = (blk >> 4) & 7;
    int b = blk >> 7;
    int tid = threadIdx.x;
    __shared__ float Cs[QC][LP], Sp[HEAD_DIM][LP];
    __shared__ float Eh[QC];
    int bl0 = b * L_SZ + c * QC;
    int row16 = tid >> 4, col4 = (tid & 15) * 4;
    const float* Sr = Sbuf + (((size_t)(b * NHEADS + h) * NCH) + c) * 4096;
#pragma unroll
    for (int r = 0; r < 4; ++r) {
        int t = r * 16 + row16;
        *(float4*)&Cs[t][col4] =
            *(const float4*)(xBC + (size_t)(bl0 + t) * CONV_DIM + D_INNER + D_STATE + col4);
        *(float4*)&Sp[t][col4] = *(const float4*)(Sr + t * 64 + col4);
    }
    if (tid < 64)
        Eh[tid] = Ebuf[(((size_t)(b * NHEADS + h) * NCH) + c) * QC + tid];
    __syncthreads();

    int tx = tid & 15, ty = tid >> 4;
    int t0 = ty * 4, p0 = tx * 4;
    float acc[4][4] = {{0.f}};
#pragma unroll
    for (int n4 = 0; n4 < 16; ++n4) {
        float4 ca[4], sb[4];
#pragma unroll
        for (int i = 0; i < 4; ++i) ca[i] = *(float4*)&Cs[t0 + i][n4 * 4];
#pragma unroll
        for (int j = 0; j < 4; ++j) sb[j] = *(float4*)&Sp[p0 + j][n4 * 4];
#pragma unroll
        for (int i = 0; i < 4; ++i)
#pragma unroll
            for (int j = 0; j < 4; ++j)
                acc[i][j] += ca[i].x * sb[j].x + ca[i].y * sb[j].y +
                             ca[i].z * sb[j].z + ca[i].w * sb[j].w;
    }
#pragma unroll
    for (int i = 0; i < 4; ++i) {
        int t = t0 + i;
        float Et = Eh[t];
        float* yrow = y + (size_t)(bl0 + t) * D_INNER + h * HEAD_DIM;
        float4 old = *(float4*)(yrow + p0);
        old.x += Et * acc[i][0];
        old.y += Et * acc[i][1];
        old.z += Et * acc[i][2];
        old.w += Et * acc[i][3];
        *(float4*)(yrow + p0) = old;
    }
}

// ---------------- gate (SiLU(z)) + RMSNorm -> bf16 ----------------
__global__ __launch_bounds__(256) void gated_rmsnorm_kernel(const float* __restrict__ zxbcdt,
                                                            const float* __restrict__ y,
                                                            const float* __restrict__ rms_w,
                                                            unsigned short* __restrict__ yn_bf) {
    int bl = blockIdx.x;
    int tid = threadIdx.x;
    __shared__ float red[4];
    __shared__ float sscale;
    float vals[4];
    float sumsq = 0.f;
#pragma unroll
    for (int i = 0; i < 4; ++i) {
        int col = tid + i * 256;
        float yv = y[(size_t)bl * D_INNER + col];
        float z = zxbcdt[(size_t)bl * D_IN_PROJ + col];
        float yz = yv * (z / (1.f + expf(-z)));
        vals[i] = yz;
        sumsq += yz * yz;
    }
#pragma unroll
    for (int off = 32; off; off >>= 1) sumsq += __shfl_xor(sumsq, off);
    int wave = tid >> 6, lane = tid & 63;
    if (lane == 0) red[wave] = sumsq;
    __syncthreads();
    if (tid == 0) {
        float t = red[0] + red[1] + red[2] + red[3];
        sscale = rsqrtf(t / (float)D_INNER + RMS_EPS);
    }
    __syncthreads();
    float sc = sscale;
#pragma unroll
    for (int i = 0; i < 4; ++i) {
        int col = tid + i * 256;
        yn_bf[(size_t)bl * D_INNER + col] = f2bf(vals[i] * sc * rms_w[col]);
    }
}

// ---------------- launch ----------------
extern "C" void kernel_launch(void* const* d_in, const int* in_sizes, int n_in,
                              void* d_out, int out_size, void* d_ws, size_t ws_size,
                              hipStream_t stream) {
    const float* u       = (const float*)d_in[0];
    const float* W_in    = (const float*)d_in[1];
    const float* conv_w  = (const float*)d_in[2];
    const float* conv_b  = (const float*)d_in[3];
    const float* dt_bias = (const float*)d_in[4];
    const float* A_log   = (const float*)d_in[5];
    const float* D_param = (const float*)d_in[6];
    const float* rms_w   = (const float*)d_in[7];
    const float* W_out   = (const float*)d_in[8];
    float* out = (float*)d_out;

    float* ws = (float*)d_ws;
    float* zxbcdt = ws;                                    // [1024][2192] f32
    float* xBC    = zxbcdt + (size_t)BL * D_IN_PROJ;       // [1024][1152] f32
    float* y      = xBC + (size_t)BL * CONV_DIM;           // [1024][1024] f32
    float* Zbuf   = y + (size_t)BL * D_INNER;              // [32][8][64][64] f32
    float* Sbuf   = Zbuf + (size_t)32 * NCH * 4096;        // [32][8][64][64] f32
    float* Ebuf   = Sbuf + (size_t)32 * NCH * 4096;        // [32][8][64] f32
    unsigned short* u_bf  = (unsigned short*)(Ebuf + 32 * NCH * QC);   // [1024][512]
    unsigned short* Wt1   = u_bf + (size_t)BL * D_MODEL;               // [2304][512]
    unsigned short* Wt2   = Wt1 + (size_t)NPAD1 * D_MODEL;             // [512][1024]
    unsigned short* yn_bf = Wt2 + (size_t)D_MODEL * D_INNER;           // [1024][1024]

    // 0) convert/transpose weights + u to bf16
    prep_kernel<<<672, 256, 0, stream>>>(W_in, W_out, u, Wt1, Wt2, u_bf);

    // 1) in_proj: zxbcdt = u @ W_in   (MFMA bf16, N=2192 predicated, Bt padded to 2304)
    gemm_mfma<<<dim3(NPAD1 / 128, BL / 128), 256, 0, stream>>>(
        u_bf, Wt1, zxbcdt, D_IN_PROJ, D_MODEL);

    // 2) causal dwconv + SiLU
    conv_silu_kernel<<<BL, 256, 0, stream>>>(zxbcdt, conv_w, conv_b, xBC);

    // 3) SSD
    ssd_passA<<<B_SZ * NCH * NHEADS, 256, 0, stream>>>(
        zxbcdt, xBC, dt_bias, A_log, D_param, y, Zbuf, Ebuf);
    ssd_passB<<<B_SZ * NHEADS, 256, 0, stream>>>(Zbuf, Ebuf, Sbuf);
    ssd_passC<<<B_SZ * NCH * NHEADS, 256, 0, stream>>>(xBC, Sbuf, Ebuf, y);

    // 4) gate + RMSNorm -> bf16
    gated_rmsnorm_kernel<<<BL, 256, 0, stream>>>(zxbcdt, y, rms_w, yn_bf);

    // 5) out_proj: out = yn @ W_out   (MFMA bf16)
    gemm_mfma<<<dim3(D_MODEL / 128, BL / 128), 256, 0, stream>>>(
        yn_bf, Wt2, out, D_MODEL, D_INNER);
}

// Round 4
// 75.463 us; speedup vs baseline: 5.7560x; 1.1541x over previous
//
#include <hip/hip_runtime.h>
#include <hip/hip_bf16.h>

// ---------------- constants ----------------
#define B_SZ 2
#define L_SZ 512
#define D_MODEL 512
#define D_INNER 1024
#define HEAD_DIM 64
#define NHEADS 16
#define D_STATE 64
#define D_CONV 3
#define CONV_DIM 1152            // D_INNER + 2*D_STATE
#define D_IN_PROJ 2192           // 2*D_INNER + 2*D_STATE + NHEADS
#define BL (B_SZ * L_SZ)         // 1024
#define RMS_EPS 1e-5f
#define QC 64                    // SSD chunk length
#define NCH 8                    // chunks per batch (L_SZ/QC)
#define LP 68                    // LDS row pitch (floats)
#define NPAD1 2304               // W_in^T padded rows (36*64)

typedef __attribute__((ext_vector_type(8))) short short8t;
typedef __attribute__((ext_vector_type(8))) unsigned short ushort8t;
typedef __attribute__((ext_vector_type(4))) float f32x4;

__device__ __forceinline__ unsigned short f2bf(float f) {
    unsigned u = __float_as_uint(f);
    u += 0x7fff + ((u >> 16) & 1);          // round-to-nearest-even
    return (unsigned short)(u >> 16);
}

__device__ __forceinline__ void gload_lds16(const void* g, void* lds) {
    __builtin_amdgcn_global_load_lds(
        (const __attribute__((address_space(1))) unsigned int*)g,
        (__attribute__((address_space(3))) unsigned int*)lds, 16, 0, 0);
}

// ---------------- prep: W_in -> Wt1[2304][512] bf16, W_out -> Wt2[512][1024] bf16, u -> bf16
__device__ __forceinline__ void transpose_tile_bf16(const float* __restrict__ src,
                                                    unsigned short* __restrict__ dst,
                                                    int K, int Nin, int tile, int ntn) {
    __shared__ float T[64][65];
    int tid = threadIdx.x;
    int nt = tile % ntn, kt = tile / ntn;
    int n0 = nt * 64, k0 = kt * 64;
#pragma unroll
    for (int rr = 0; rr < 4; ++rr) {
        int k = k0 + (tid >> 4) + rr * 16;
        int nn = (tid & 15) * 4;
#pragma unroll
        for (int q = 0; q < 4; ++q) {
            int n = n0 + nn + q;
            T[(tid >> 4) + rr * 16][nn + q] = (n < Nin) ? src[(size_t)k * Nin + n] : 0.f;
        }
    }
    __syncthreads();
    int nn2 = tid >> 2, kc = tid & 3;
    unsigned short ov[16];
#pragma unroll
    for (int j = 0; j < 16; ++j) ov[j] = f2bf(T[kc * 16 + j][nn2]);
    unsigned short* p = dst + (size_t)(n0 + nn2) * K + k0 + kc * 16;
    *(ushort8t*)p = *(ushort8t*)&ov[0];
    *(ushort8t*)(p + 8) = *(ushort8t*)&ov[8];
}

__global__ __launch_bounds__(256) void prep_kernel(const float* __restrict__ W_in,
                                                   const float* __restrict__ W_out,
                                                   const float* __restrict__ u,
                                                   unsigned short* __restrict__ Wt1,
                                                   unsigned short* __restrict__ Wt2,
                                                   unsigned short* __restrict__ u_bf) {
    int bid = blockIdx.x;
    if (bid < 288) {                    // W_in [512][2192] -> Wt1 [2304][512]
        transpose_tile_bf16(W_in, Wt1, D_MODEL, D_IN_PROJ, bid, 36);
    } else if (bid < 416) {             // W_out [1024][512] -> Wt2 [512][1024]
        transpose_tile_bf16(W_out, Wt2, D_INNER, D_MODEL, bid - 288, 8);
    } else {                            // u -> bf16
        int i = ((bid - 416) * 256 + threadIdx.x) * 8;
        float4 v0 = *(const float4*)(u + i);
        float4 v1 = *(const float4*)(u + i + 4);
        unsigned short ov[8] = {f2bf(v0.x), f2bf(v0.y), f2bf(v0.z), f2bf(v0.w),
                                f2bf(v1.x), f2bf(v1.y), f2bf(v1.z), f2bf(v1.w)};
        *(ushort8t*)(u_bf + i) = *(ushort8t*)&ov[0];
    }
}

// ---------------- bf16 MFMA GEMM, small-shape: C[M,N] = A[M,K] * Bt[N,K]^T ----------------
// 64x64 tile, BK=64, 4 waves (2x2), each wave 32x32 (2x2 frags of 16x16x32).
// LDS rows are 128B; XOR-swizzle cb ^= (row&7)<<4 applied on BOTH the global
// source address (stage) and the ds_read address (rule: both-sides-or-neither).
__global__ __launch_bounds__(256) void gemm_mfma64(const unsigned short* __restrict__ A,
                                                   const unsigned short* __restrict__ Bt,
                                                   float* __restrict__ C,
                                                   int N, int K) {
    __shared__ char sm[32768];          // [2 buf][A:8192 | B:8192]
    int tid = threadIdx.x;
    int w = tid >> 6, l = tid & 63;
    int m0 = blockIdx.y * 64, n0 = blockIdx.x * 64;
    int wm = w >> 1, wn = w & 1;

    f32x4 acc[2][2];
#pragma unroll
    for (int i = 0; i < 2; ++i)
#pragma unroll
        for (int j = 0; j < 2; ++j) acc[i][j] = (f32x4){0.f, 0.f, 0.f, 0.f};

    // stage a 64x64 bf16 tile (8KB): 8 chunks of 1KB; wave w stages chunks 2w, 2w+1.
    // LDS linear: offset o = c*1024 + lane*16 -> row = o>>7, col_byte = o&127.
    // Source col pre-swizzled so swizzled ds_read sees the right data.
    auto stage = [&](const unsigned short* src, int row0, int k0, char* dst) {
#pragma unroll
        for (int p = 0; p < 2; ++p) {
            int c = w * 2 + p;
            int row = c * 8 + (l >> 3);
            int scb = ((l & 7) << 4) ^ ((row & 7) << 4);
            gload_lds16(src + (size_t)(row0 + row) * K + k0 + (scb >> 1), dst + c * 1024);
        }
    };

    int nkt = K / 64;
    int cur = 0;
    stage(A, m0, 0, sm);
    stage(Bt, n0, 0, sm + 8192);
    __syncthreads();

    for (int kt = 0; kt < nkt; ++kt) {
        if (kt + 1 < nkt) {
            stage(A, m0, (kt + 1) * 64, sm + (cur ^ 1) * 16384);
            stage(Bt, n0, (kt + 1) * 64, sm + (cur ^ 1) * 16384 + 8192);
        }
        const char* Ab = sm + cur * 16384;
        const char* Bb = Ab + 8192;
#pragma unroll
        for (int kk = 0; kk < 2; ++kk) {
            short8t af[2], bf[2];
#pragma unroll
            for (int i = 0; i < 2; ++i) {
                int r = wm * 32 + i * 16 + (l & 15);
                int cb = (kk * 64 + (l >> 4) * 16) ^ ((r & 7) << 4);
                af[i] = *(const short8t*)(Ab + r * 128 + cb);
            }
#pragma unroll
            for (int j = 0; j < 2; ++j) {
                int r = wn * 32 + j * 16 + (l & 15);
                int cb = (kk * 64 + (l >> 4) * 16) ^ ((r & 7) << 4);
                bf[j] = *(const short8t*)(Bb + r * 128 + cb);
            }
#pragma unroll
            for (int i = 0; i < 2; ++i)
#pragma unroll
                for (int j = 0; j < 2; ++j)
                    acc[i][j] = __builtin_amdgcn_mfma_f32_16x16x32_bf16(af[i], bf[j], acc[i][j], 0, 0, 0);
        }
        __syncthreads();
        cur ^= 1;
    }

#pragma unroll
    for (int i = 0; i < 2; ++i)
#pragma unroll
        for (int j = 0; j < 2; ++j) {
            int row = m0 + wm * 32 + i * 16 + (l >> 4) * 4;
            int col = n0 + wn * 32 + j * 16 + (l & 15);
            if (col < N) {
#pragma unroll
                for (int r = 0; r < 4; ++r)
                    C[(size_t)(row + r) * N + col] = acc[i][j][r];
            }
        }
}

// ---------------- causal depthwise conv (k=3) + bias + SiLU ----------------
__global__ __launch_bounds__(256) void conv_silu_kernel(const float* __restrict__ zxbcdt,
                                                        const float* __restrict__ conv_w,
                                                        const float* __restrict__ conv_b,
                                                        float* __restrict__ xBC) {
    int bl = blockIdx.x;
    int l = bl & (L_SZ - 1);
    const float* base = zxbcdt + (size_t)bl * D_IN_PROJ + D_INNER;
    for (int c = threadIdx.x; c < CONV_DIM; c += blockDim.x) {
        float w0 = conv_w[c * 3 + 0], w1 = conv_w[c * 3 + 1], w2 = conv_w[c * 3 + 2];
        float acc = conv_b[c] + w2 * base[c];
        if (l >= 1) acc += w1 * base[c - D_IN_PROJ];
        if (l >= 2) acc += w0 * base[c - 2 * D_IN_PROJ];
        float s = acc / (1.f + expf(-acc));
        xBC[(size_t)bl * CONV_DIM + c] = s;
    }
}

// ---------------- SSD pass A ----------------
__global__ __launch_bounds__(256) void ssd_passA(const float* __restrict__ zxbcdt,
                                                 const float* __restrict__ xBC,
                                                 const float* __restrict__ dt_bias,
                                                 const float* __restrict__ A_log,
                                                 const float* __restrict__ D_param,
                                                 float* __restrict__ y,
                                                 float* __restrict__ Zbuf,
                                                 float* __restrict__ Ebuf) {
    int blk = blockIdx.x;          // b*128 + c*16 + h
    int h = blk & 15;
    int c = (blk >> 4) & 7;
    int b = blk >> 7;
    int tid = threadIdx.x;

    __shared__ float Bs[QC][LP], Cs[QC][LP], XDs[QC][LP], Ps[QC][LP];
    __shared__ float csh[QC], dts[QC], wh[QC];

    int bl0 = b * L_SZ + c * QC;

    if (tid < 64) {
        int t = tid;
        float draw = zxbcdt[(size_t)(bl0 + t) * D_IN_PROJ + 2 * D_INNER + 2 * D_STATE + h];
        float dtv = draw + dt_bias[h];
        dtv = (dtv > 20.f) ? dtv : log1pf(expf(dtv));
        float A = -expf(A_log[h]);
        float a = A * dtv;
        float cs = a;
#pragma unroll
        for (int off = 1; off < 64; off <<= 1) {
            float tmp = __shfl_up(cs, off);
            if (t >= off) cs += tmp;
        }
        float cs63 = __shfl(cs, 63);
        dts[t] = dtv;
        csh[t] = cs;
        wh[t] = __expf(cs63 - cs);
        Ebuf[(((size_t)(b * NHEADS + h) * NCH) + c) * QC + t] = __expf(cs);
    }

    int row16 = tid >> 4;
    int col4 = (tid & 15) * 4;
#pragma unroll
    for (int r = 0; r < 4; ++r) {
        int t = r * 16 + row16;
        const float* xrow = xBC + (size_t)(bl0 + t) * CONV_DIM;
        *(float4*)&Bs[t][col4] = *(const float4*)(xrow + D_INNER + col4);
        *(float4*)&Cs[t][col4] = *(const float4*)(xrow + D_INNER + D_STATE + col4);
    }
    __syncthreads();
#pragma unroll
    for (int r = 0; r < 4; ++r) {
        int t = r * 16 + row16;
        const float* xrow = xBC + (size_t)(bl0 + t) * CONV_DIM + h * HEAD_DIM;
        float4 xv = *(const float4*)(xrow + col4);
        float d = dts[t];
        xv.x *= d; xv.y *= d; xv.z *= d; xv.w *= d;
        *(float4*)&XDs[t][col4] = xv;
    }
    __syncthreads();

    int tx = tid & 15, ty = tid >> 4;
    int t0 = ty * 4, s0 = tx * 4;

    {
        float g[4][4] = {{0.f}};
#pragma unroll
        for (int n4 = 0; n4 < 16; ++n4) {
            float4 ca[4], cb[4];
#pragma unroll
            for (int i = 0; i < 4; ++i) ca[i] = *(float4*)&Cs[t0 + i][n4 * 4];
#pragma unroll
            for (int j = 0; j < 4; ++j) cb[j] = *(float4*)&Bs[s0 + j][n4 * 4];
#pragma unroll
            for (int i = 0; i < 4; ++i)
#pragma unroll
                for (int j = 0; j < 4; ++j)
                    g[i][j] += ca[i].x * cb[j].x + ca[i].y * cb[j].y +
                               ca[i].z * cb[j].z + ca[i].w * cb[j].w;
        }
#pragma unroll
        for (int i = 0; i < 4; ++i) {
            int t = t0 + i; float cst = csh[t];
#pragma unroll
            for (int j = 0; j < 4; ++j) {
                int s = s0 + j;
                Ps[t][s] = (s <= t) ? g[i][j] * __expf(cst - csh[s]) : 0.f;
            }
        }
    }
    __syncthreads();

    {
        int p0 = tx * 4;
        float yv[4][4] = {{0.f}};
#pragma unroll
        for (int s4 = 0; s4 < 16; ++s4) {
            float4 pa[4], xb[4];
#pragma unroll
            for (int i = 0; i < 4; ++i) pa[i] = *(float4*)&Ps[t0 + i][s4 * 4];
#pragma unroll
            for (int k = 0; k < 4; ++k) xb[k] = *(float4*)&XDs[s4 * 4 + k][p0];
#pragma unroll
            for (int i = 0; i < 4; ++i) {
                float pav[4] = {pa[i].x, pa[i].y, pa[i].z, pa[i].w};
#pragma unroll
                for (int k = 0; k < 4; ++k) {
                    yv[i][0] += pav[k] * xb[k].x;
                    yv[i][1] += pav[k] * xb[k].y;
                    yv[i][2] += pav[k] * xb[k].z;
                    yv[i][3] += pav[k] * xb[k].w;
                }
            }
        }
        float Dp = D_param[h];
#pragma unroll
        for (int i = 0; i < 4; ++i) {
            int t = t0 + i;
            const float* xrow = xBC + (size_t)(bl0 + t) * CONV_DIM + h * HEAD_DIM;
            float* yrow = y + (size_t)(bl0 + t) * D_INNER + h * HEAD_DIM;
            float4 xv = *(const float4*)(xrow + p0);
            float4 o = make_float4(yv[i][0] + Dp * xv.x, yv[i][1] + Dp * xv.y,
                                   yv[i][2] + Dp * xv.z, yv[i][3] + Dp * xv.w);
            *(float4*)(yrow + p0) = o;
        }
    }

    {
        float zv[4][4] = {{0.f}};
#pragma unroll
        for (int t4 = 0; t4 < 16; ++t4) {
            float4 xa[4], bb[4];
#pragma unroll
            for (int k = 0; k < 4; ++k) {
                int t = t4 * 4 + k;
                xa[k] = *(float4*)&XDs[t][t0];
                float4 bv = *(float4*)&Bs[t][s0];
                float wt = wh[t];
                bv.x *= wt; bv.y *= wt; bv.z *= wt; bv.w *= wt;
                bb[k] = bv;
            }
#pragma unroll
            for (int k = 0; k < 4; ++k) {
                float xav[4] = {xa[k].x, xa[k].y, xa[k].z, xa[k].w};
#pragma unroll
                for (int i = 0; i < 4; ++i) {
                    zv[i][0] += xav[i] * bb[k].x;
                    zv[i][1] += xav[i] * bb[k].y;
                    zv[i][2] += xav[i] * bb[k].z;
                    zv[i][3] += xav[i] * bb[k].w;
                }
            }
        }
        float* Zr = Zbuf + (((size_t)(b * NHEADS + h) * NCH) + c) * (HEAD_DIM * D_STATE);
#pragma unroll
        for (int i = 0; i < 4; ++i)
            *(float4*)(Zr + (t0 + i) * D_STATE + s0) =
                make_float4(zv[i][0], zv[i][1], zv[i][2], zv[i][3]);
    }
}

// ---------------- SSD pass B ----------------
__global__ __launch_bounds__(256) void ssd_passB(const float* __restrict__ Zbuf,
                                                 const float* __restrict__ Ebuf,
                                                 float* __restrict__ Sbuf) {
    int bh = blockIdx.x;
    int tid = threadIdx.x;
    const float* Zb = Zbuf + (size_t)bh * NCH * 4096;
    float* Sb = Sbuf + (size_t)bh * NCH * 4096;
    const float* Eb = Ebuf + (size_t)bh * NCH * QC;
    float4 S[4];
#pragma unroll
    for (int k = 0; k < 4; ++k) S[k] = make_float4(0.f, 0.f, 0.f, 0.f);
    for (int c = 0; c < NCH; ++c) {
#pragma unroll
        for (int k = 0; k < 4; ++k)
            *(float4*)(Sb + (size_t)c * 4096 + k * 1024 + tid * 4) = S[k];
        float dec = Eb[c * QC + 63];
#pragma unroll
        for (int k = 0; k < 4; ++k) {
            float4 z = *(const float4*)(Zb + (size_t)c * 4096 + k * 1024 + tid * 4);
            S[k].x = dec * S[k].x + z.x;
            S[k].y = dec * S[k].y + z.y;
            S[k].z = dec * S[k].z + z.z;
            S[k].w = dec * S[k].w + z.w;
        }
    }
}

// ---------------- SSD pass C ----------------
__global__ __launch_bounds__(256) void ssd_passC(const float* __restrict__ xBC,
                                                 const float* __restrict__ Sbuf,
                                                 const float* __restrict__ Ebuf,
                                                 float* __restrict__ y) {
    int blk = blockIdx.x;
    int h = blk & 15;
    int c = (blk >> 4) & 7;
    int b = blk >> 7;
    int tid = threadIdx.x;
    __shared__ float Cs[QC][LP], Sp[HEAD_DIM][LP];
    __shared__ float Eh[QC];
    int bl0 = b * L_SZ + c * QC;
    int row16 = tid >> 4, col4 = (tid & 15) * 4;
    const float* Sr = Sbuf + (((size_t)(b * NHEADS + h) * NCH) + c) * 4096;
#pragma unroll
    for (int r = 0; r < 4; ++r) {
        int t = r * 16 + row16;
        *(float4*)&Cs[t][col4] =
            *(const float4*)(xBC + (size_t)(bl0 + t) * CONV_DIM + D_INNER + D_STATE + col4);
        *(float4*)&Sp[t][col4] = *(const float4*)(Sr + t * 64 + col4);
    }
    if (tid < 64)
        Eh[tid] = Ebuf[(((size_t)(b * NHEADS + h) * NCH) + c) * QC + tid];
    __syncthreads();

    int tx = tid & 15, ty = tid >> 4;
    int t0 = ty * 4, p0 = tx * 4;
    float acc[4][4] = {{0.f}};
#pragma unroll
    for (int n4 = 0; n4 < 16; ++n4) {
        float4 ca[4], sb[4];
#pragma unroll
        for (int i = 0; i < 4; ++i) ca[i] = *(float4*)&Cs[t0 + i][n4 * 4];
#pragma unroll
        for (int j = 0; j < 4; ++j) sb[j] = *(float4*)&Sp[p0 + j][n4 * 4];
#pragma unroll
        for (int i = 0; i < 4; ++i)
#pragma unroll
            for (int j = 0; j < 4; ++j)
                acc[i][j] += ca[i].x * sb[j].x + ca[i].y * sb[j].y +
                             ca[i].z * sb[j].z + ca[i].w * sb[j].w;
    }
#pragma unroll
    for (int i = 0; i < 4; ++i) {
        int t = t0 + i;
        float Et = Eh[t];
        float* yrow = y + (size_t)(bl0 + t) * D_INNER + h * HEAD_DIM;
        float4 old = *(float4*)(yrow + p0);
        old.x += Et * acc[i][0];
        old.y += Et * acc[i][1];
        old.z += Et * acc[i][2];
        old.w += Et * acc[i][3];
        *(float4*)(yrow + p0) = old;
    }
}

// ---------------- gate (SiLU(z)) + RMSNorm -> bf16 ----------------
__global__ __launch_bounds__(256) void gated_rmsnorm_kernel(const float* __restrict__ zxbcdt,
                                                            const float* __restrict__ y,
                                                            const float* __restrict__ rms_w,
                                                            unsigned short* __restrict__ yn_bf) {
    int bl = blockIdx.x;
    int tid = threadIdx.x;
    __shared__ float red[4];
    __shared__ float sscale;
    float vals[4];
    float sumsq = 0.f;
#pragma unroll
    for (int i = 0; i < 4; ++i) {
        int col = tid + i * 256;
        float yv = y[(size_t)bl * D_INNER + col];
        float z = zxbcdt[(size_t)bl * D_IN_PROJ + col];
        float yz = yv * (z / (1.f + expf(-z)));
        vals[i] = yz;
        sumsq += yz * yz;
    }
#pragma unroll
    for (int off = 32; off; off >>= 1) sumsq += __shfl_xor(sumsq, off);
    int wave = tid >> 6, lane = tid & 63;
    if (lane == 0) red[wave] = sumsq;
    __syncthreads();
    if (tid == 0) {
        float t = red[0] + red[1] + red[2] + red[3];
        sscale = rsqrtf(t / (float)D_INNER + RMS_EPS);
    }
    __syncthreads();
    float sc = sscale;
#pragma unroll
    for (int i = 0; i < 4; ++i) {
        int col = tid + i * 256;
        yn_bf[(size_t)bl * D_INNER + col] = f2bf(vals[i] * sc * rms_w[col]);
    }
}

// ---------------- launch ----------------
extern "C" void kernel_launch(void* const* d_in, const int* in_sizes, int n_in,
                              void* d_out, int out_size, void* d_ws, size_t ws_size,
                              hipStream_t stream) {
    const float* u       = (const float*)d_in[0];
    const float* W_in    = (const float*)d_in[1];
    const float* conv_w  = (const float*)d_in[2];
    const float* conv_b  = (const float*)d_in[3];
    const float* dt_bias = (const float*)d_in[4];
    const float* A_log   = (const float*)d_in[5];
    const float* D_param = (const float*)d_in[6];
    const float* rms_w   = (const float*)d_in[7];
    const float* W_out   = (const float*)d_in[8];
    float* out = (float*)d_out;

    float* ws = (float*)d_ws;
    float* zxbcdt = ws;                                    // [1024][2192] f32
    float* xBC    = zxbcdt + (size_t)BL * D_IN_PROJ;       // [1024][1152] f32
    float* y      = xBC + (size_t)BL * CONV_DIM;           // [1024][1024] f32
    float* Zbuf   = y + (size_t)BL * D_INNER;              // [32][8][64][64] f32
    float* Sbuf   = Zbuf + (size_t)32 * NCH * 4096;        // [32][8][64][64] f32
    float* Ebuf   = Sbuf + (size_t)32 * NCH * 4096;        // [32][8][64] f32
    unsigned short* u_bf  = (unsigned short*)(Ebuf + 32 * NCH * QC);   // [1024][512]
    unsigned short* Wt1   = u_bf + (size_t)BL * D_MODEL;               // [2304][512]
    unsigned short* Wt2   = Wt1 + (size_t)NPAD1 * D_MODEL;             // [512][1024]
    unsigned short* yn_bf = Wt2 + (size_t)D_MODEL * D_INNER;           // [1024][1024]

    // 0) convert/transpose weights + u to bf16
    prep_kernel<<<672, 256, 0, stream>>>(W_in, W_out, u, Wt1, Wt2, u_bf);

    // 1) in_proj: zxbcdt = u @ W_in   (MFMA bf16, 64x64 tiles, 576 blocks)
    gemm_mfma64<<<dim3(NPAD1 / 64, BL / 64), 256, 0, stream>>>(
        u_bf, Wt1, zxbcdt, D_IN_PROJ, D_MODEL);

    // 2) causal dwconv + SiLU
    conv_silu_kernel<<<BL, 256, 0, stream>>>(zxbcdt, conv_w, conv_b, xBC);

    // 3) SSD
    ssd_passA<<<B_SZ * NCH * NHEADS, 256, 0, stream>>>(
        zxbcdt, xBC, dt_bias, A_log, D_param, y, Zbuf, Ebuf);
    ssd_passB<<<B_SZ * NHEADS, 256, 0, stream>>>(Zbuf, Ebuf, Sbuf);
    ssd_passC<<<B_SZ * NCH * NHEADS, 256, 0, stream>>>(xBC, Sbuf, Ebuf, y);

    // 4) gate + RMSNorm -> bf16
    gated_rmsnorm_kernel<<<BL, 256, 0, stream>>>(zxbcdt, y, rms_w, yn_bf);

    // 5) out_proj: out = yn @ W_out   (MFMA bf16, 64x64 tiles, 128 blocks)
    gemm_mfma64<<<dim3(D_MODEL / 64, BL / 64), 256, 0, stream>>>(
        yn_bf, Wt2, out, D_MODEL, D_INNER);
}

// Round 5
// 63.641 us; speedup vs baseline: 6.8252x; 1.1858x over previous
//
#include <hip/hip_runtime.h>
#include <hip/hip_bf16.h>

// ---------------- constants ----------------
#define B_SZ 2
#define L_SZ 512
#define D_MODEL 512
#define D_INNER 1024
#define HEAD_DIM 64
#define NHEADS 16
#define D_STATE 64
#define D_CONV 3
#define CONV_DIM 1152            // D_INNER + 2*D_STATE
#define D_IN_PROJ 2192           // 2*D_INNER + 2*D_STATE + NHEADS
#define BL (B_SZ * L_SZ)         // 1024
#define RMS_EPS 1e-5f
#define QC 64                    // SSD chunk length
#define NCH 8                    // chunks per batch (L_SZ/QC)
#define LP 68                    // LDS row pitch (floats)
#define NPAD1 2304               // W_in^T padded rows (36*64)

typedef __attribute__((ext_vector_type(8))) short short8t;
typedef __attribute__((ext_vector_type(8))) unsigned short ushort8t;
typedef __attribute__((ext_vector_type(4))) float f32x4;

__device__ __forceinline__ unsigned short f2bf(float f) {
    unsigned u = __float_as_uint(f);
    u += 0x7fff + ((u >> 16) & 1);          // round-to-nearest-even
    return (unsigned short)(u >> 16);
}

__device__ __forceinline__ void gload_lds16(const void* g, void* lds) {
    __builtin_amdgcn_global_load_lds(
        (const __attribute__((address_space(1))) unsigned int*)g,
        (__attribute__((address_space(3))) unsigned int*)lds, 16, 0, 0);
}

// ---------------- prep: W_in -> Wt1[2304][512] bf16, W_out -> Wt2[512][1024] bf16, u -> bf16
__device__ __forceinline__ void transpose_tile_bf16(const float* __restrict__ src,
                                                    unsigned short* __restrict__ dst,
                                                    int K, int Nin, int tile, int ntn) {
    __shared__ float T[64][65];
    int tid = threadIdx.x;
    int nt = tile % ntn, kt = tile / ntn;
    int n0 = nt * 64, k0 = kt * 64;
#pragma unroll
    for (int rr = 0; rr < 4; ++rr) {
        int k = k0 + (tid >> 4) + rr * 16;
        int nn = (tid & 15) * 4;
#pragma unroll
        for (int q = 0; q < 4; ++q) {
            int n = n0 + nn + q;
            T[(tid >> 4) + rr * 16][nn + q] = (n < Nin) ? src[(size_t)k * Nin + n] : 0.f;
        }
    }
    __syncthreads();
    int nn2 = tid >> 2, kc = tid & 3;
    unsigned short ov[16];
#pragma unroll
    for (int j = 0; j < 16; ++j) ov[j] = f2bf(T[kc * 16 + j][nn2]);
    unsigned short* p = dst + (size_t)(n0 + nn2) * K + k0 + kc * 16;
    *(ushort8t*)p = *(ushort8t*)&ov[0];
    *(ushort8t*)(p + 8) = *(ushort8t*)&ov[8];
}

__global__ __launch_bounds__(256) void prep_kernel(const float* __restrict__ W_in,
                                                   const float* __restrict__ W_out,
                                                   const float* __restrict__ u,
                                                   unsigned short* __restrict__ Wt1,
                                                   unsigned short* __restrict__ Wt2,
                                                   unsigned short* __restrict__ u_bf) {
    int bid = blockIdx.x;
    if (bid < 288) {                    // W_in [512][2192] -> Wt1 [2304][512]
        transpose_tile_bf16(W_in, Wt1, D_MODEL, D_IN_PROJ, bid, 36);
    } else if (bid < 416) {             // W_out [1024][512] -> Wt2 [512][1024]
        transpose_tile_bf16(W_out, Wt2, D_INNER, D_MODEL, bid - 288, 8);
    } else {                            // u -> bf16
        int i = ((bid - 416) * 256 + threadIdx.x) * 8;
        float4 v0 = *(const float4*)(u + i);
        float4 v1 = *(const float4*)(u + i + 4);
        unsigned short ov[8] = {f2bf(v0.x), f2bf(v0.y), f2bf(v0.z), f2bf(v0.w),
                                f2bf(v1.x), f2bf(v1.y), f2bf(v1.z), f2bf(v1.w)};
        *(ushort8t*)(u_bf + i) = *(ushort8t*)&ov[0];
    }
}

// ---------------- bf16 MFMA GEMM: C[M,N] = A[M,K] * Bt[N,K]^T ----------------
// 64x64 tile, BK=64, 4 waves, wave = 32x32 (2x2 frags of 16x16x32).
// 3-deep LDS pipeline with counted vmcnt (T3/T4): per wave 4 loads/tile,
// steady state 12 outstanding; vmcnt(8) => oldest tile resident. Raw barriers
// (no vmcnt(0) drain). 3 buffers => stage target (kt+2)%3 != read buffer kt%3.
__global__ __launch_bounds__(256) void gemm_mfma64(const unsigned short* __restrict__ A,
                                                   const unsigned short* __restrict__ Bt,
                                                   float* __restrict__ C,
                                                   int N, int K) {
    __shared__ char sm[49152];          // 3 buf x (A:8192 | B:8192)
    int tid = threadIdx.x;
    int w = tid >> 6, l = tid & 63;
    int m0 = blockIdx.y * 64, n0 = blockIdx.x * 64;
    int wm = w >> 1, wn = w & 1;

    f32x4 acc[2][2];
#pragma unroll
    for (int i = 0; i < 2; ++i)
#pragma unroll
        for (int j = 0; j < 2; ++j) acc[i][j] = (f32x4){0.f, 0.f, 0.f, 0.f};

    // stage 64x64 bf16 tile (8KB): 8 chunks of 1KB; wave w stages chunks 2w,2w+1.
    // XOR swizzle (row&7)<<4 pre-applied to the global source (both-sides rule).
    auto stage = [&](const unsigned short* src, int row0, int k0, char* dst) {
#pragma unroll
        for (int p = 0; p < 2; ++p) {
            int c = w * 2 + p;
            int row = c * 8 + (l >> 3);
            int scb = ((l & 7) << 4) ^ ((row & 7) << 4);
            gload_lds16(src + (size_t)(row0 + row) * K + k0 + (scb >> 1), dst + c * 1024);
        }
    };

    int nkt = K / 64;
    stage(A, m0, 0, sm);
    stage(Bt, n0, 0, sm + 8192);
    if (nkt > 1) {
        stage(A, m0, 64, sm + 16384);
        stage(Bt, n0, 64, sm + 16384 + 8192);
    }

    for (int kt = 0; kt < nkt; ++kt) {
        if (kt + 2 < nkt) {
            char* d = sm + ((kt + 2) % 3) * 16384;
            stage(A, m0, (kt + 2) * 64, d);
            stage(Bt, n0, (kt + 2) * 64, d + 8192);
        }
        int inflight = nkt - 1 - kt;
        if (inflight >= 2)      asm volatile("s_waitcnt vmcnt(8)" ::: "memory");
        else if (inflight == 1) asm volatile("s_waitcnt vmcnt(4)" ::: "memory");
        else                    asm volatile("s_waitcnt vmcnt(0)" ::: "memory");
        __builtin_amdgcn_s_barrier();     // all waves' tile-kt loads resident

        const char* Ab = sm + (kt % 3) * 16384;
        const char* Bb = Ab + 8192;
#pragma unroll
        for (int kk = 0; kk < 2; ++kk) {
            short8t af[2], bf[2];
#pragma unroll
            for (int i = 0; i < 2; ++i) {
                int r = wm * 32 + i * 16 + (l & 15);
                int cb = (kk * 64 + (l >> 4) * 16) ^ ((r & 7) << 4);
                af[i] = *(const short8t*)(Ab + r * 128 + cb);
            }
#pragma unroll
            for (int j = 0; j < 2; ++j) {
                int r = wn * 32 + j * 16 + (l & 15);
                int cb = (kk * 64 + (l >> 4) * 16) ^ ((r & 7) << 4);
                bf[j] = *(const short8t*)(Bb + r * 128 + cb);
            }
#pragma unroll
            for (int i = 0; i < 2; ++i)
#pragma unroll
                for (int j = 0; j < 2; ++j)
                    acc[i][j] = __builtin_amdgcn_mfma_f32_16x16x32_bf16(af[i], bf[j], acc[i][j], 0, 0, 0);
        }
        __builtin_amdgcn_s_barrier();     // guard LDS reuse before next stage
    }

#pragma unroll
    for (int i = 0; i < 2; ++i)
#pragma unroll
        for (int j = 0; j < 2; ++j) {
            int row = m0 + wm * 32 + i * 16 + (l >> 4) * 4;
            int col = n0 + wn * 32 + j * 16 + (l & 15);
            if (col < N) {
#pragma unroll
                for (int r = 0; r < 4; ++r)
                    C[(size_t)(row + r) * N + col] = acc[i][j][r];
            }
        }
}

// conv+SiLU of 4 consecutive channels at one row; gl = seq position (causal clamp)
__device__ __forceinline__ float4 conv4(const float* __restrict__ prow, int gl, int zxcol,
                                        const float* __restrict__ conv_w,
                                        const float* __restrict__ conv_b) {
    float4 v2 = *(const float4*)(prow + zxcol);
    float4 v1 = make_float4(0.f, 0.f, 0.f, 0.f), v0 = v1;
    if (gl >= 1) v1 = *(const float4*)(prow - D_IN_PROJ + zxcol);
    if (gl >= 2) v0 = *(const float4*)(prow - 2 * D_IN_PROJ + zxcol);
    int ch = zxcol - D_INNER;
    float4 o;
    float a;
    a = conv_b[ch+0] + conv_w[(ch+0)*3]*v0.x + conv_w[(ch+0)*3+1]*v1.x + conv_w[(ch+0)*3+2]*v2.x;
    o.x = a / (1.f + __expf(-a));
    a = conv_b[ch+1] + conv_w[(ch+1)*3]*v0.y + conv_w[(ch+1)*3+1]*v1.y + conv_w[(ch+1)*3+2]*v2.y;
    o.y = a / (1.f + __expf(-a));
    a = conv_b[ch+2] + conv_w[(ch+2)*3]*v0.z + conv_w[(ch+2)*3+1]*v1.z + conv_w[(ch+2)*3+2]*v2.z;
    o.z = a / (1.f + __expf(-a));
    a = conv_b[ch+3] + conv_w[(ch+3)*3]*v0.w + conv_w[(ch+3)*3+1]*v1.w + conv_w[(ch+3)*3+2]*v2.w;
    o.w = a / (1.f + __expf(-a));
    return o;
}

// ---------------- SSD pass A (conv fused) ----------------
__global__ __launch_bounds__(256) void ssd_passA(const float* __restrict__ zxbcdt,
                                                 const float* __restrict__ conv_w,
                                                 const float* __restrict__ conv_b,
                                                 const float* __restrict__ dt_bias,
                                                 const float* __restrict__ A_log,
                                                 const float* __restrict__ D_param,
                                                 float* __restrict__ y,
                                                 float* __restrict__ Zbuf,
                                                 float* __restrict__ Ebuf) {
    int blk = blockIdx.x;          // b*128 + c*16 + h
    int h = blk & 15;
    int c = (blk >> 4) & 7;
    int b = blk >> 7;
    int tid = threadIdx.x;

    __shared__ float Bs[QC][LP], Cs[QC][LP], XDs[QC][LP], Ps[QC][LP];
    __shared__ float csh[QC], dts[QC], wh[QC];

    int bl0 = b * L_SZ + c * QC;
    const float* zb = zxbcdt + (size_t)bl0 * D_IN_PROJ;

    if (tid < 64) {
        int t = tid;
        float draw = zb[(size_t)t * D_IN_PROJ + 2 * D_INNER + 2 * D_STATE + h];
        float dtv = draw + dt_bias[h];
        dtv = (dtv > 20.f) ? dtv : log1pf(expf(dtv));
        float A = -expf(A_log[h]);
        float a = A * dtv;
        float cs = a;
#pragma unroll
        for (int off = 1; off < 64; off <<= 1) {
            float tmp = __shfl_up(cs, off);
            if (t >= off) cs += tmp;
        }
        float cs63 = __shfl(cs, 63);
        dts[t] = dtv;
        csh[t] = cs;
        wh[t] = __expf(cs63 - cs);
        Ebuf[(((size_t)(b * NHEADS + h) * NCH) + c) * QC + t] = __expf(cs);
    }

    int row16 = tid >> 4;
    int col4 = (tid & 15) * 4;
#pragma unroll
    for (int r = 0; r < 4; ++r) {
        int t = r * 16 + row16;
        int gl = c * QC + t;
        const float* prow = zb + (size_t)t * D_IN_PROJ;
        *(float4*)&Bs[t][col4] = conv4(prow, gl, D_INNER + D_INNER + col4, conv_w, conv_b);
        *(float4*)&Cs[t][col4] = conv4(prow, gl, D_INNER + D_INNER + D_STATE + col4, conv_w, conv_b);
    }
    __syncthreads();               // dts visible
#pragma unroll
    for (int r = 0; r < 4; ++r) {
        int t = r * 16 + row16;
        int gl = c * QC + t;
        const float* prow = zb + (size_t)t * D_IN_PROJ;
        float4 xv = conv4(prow, gl, D_INNER + h * HEAD_DIM + col4, conv_w, conv_b);
        float d = dts[t];
        xv.x *= d; xv.y *= d; xv.z *= d; xv.w *= d;
        *(float4*)&XDs[t][col4] = xv;
    }
    __syncthreads();

    int tx = tid & 15, ty = tid >> 4;
    int t0 = ty * 4, s0 = tx * 4;

    {   // G = C B^T, mask+decay -> Ps
        float g[4][4] = {{0.f}};
#pragma unroll
        for (int n4 = 0; n4 < 16; ++n4) {
            float4 ca[4], cb[4];
#pragma unroll
            for (int i = 0; i < 4; ++i) ca[i] = *(float4*)&Cs[t0 + i][n4 * 4];
#pragma unroll
            for (int j = 0; j < 4; ++j) cb[j] = *(float4*)&Bs[s0 + j][n4 * 4];
#pragma unroll
            for (int i = 0; i < 4; ++i)
#pragma unroll
                for (int j = 0; j < 4; ++j)
                    g[i][j] += ca[i].x * cb[j].x + ca[i].y * cb[j].y +
                               ca[i].z * cb[j].z + ca[i].w * cb[j].w;
        }
#pragma unroll
        for (int i = 0; i < 4; ++i) {
            int t = t0 + i; float cst = csh[t];
#pragma unroll
            for (int j = 0; j < 4; ++j) {
                int s = s0 + j;
                Ps[t][s] = (s <= t) ? g[i][j] * __expf(cst - csh[s]) : 0.f;
            }
        }
    }
    __syncthreads();

    {   // Y_diag = P @ XD + (D/dt)*XD
        int p0 = tx * 4;
        float yv[4][4] = {{0.f}};
#pragma unroll
        for (int s4 = 0; s4 < 16; ++s4) {
            float4 pa[4], xb[4];
#pragma unroll
            for (int i = 0; i < 4; ++i) pa[i] = *(float4*)&Ps[t0 + i][s4 * 4];
#pragma unroll
            for (int k = 0; k < 4; ++k) xb[k] = *(float4*)&XDs[s4 * 4 + k][p0];
#pragma unroll
            for (int i = 0; i < 4; ++i) {
                float pav[4] = {pa[i].x, pa[i].y, pa[i].z, pa[i].w};
#pragma unroll
                for (int k = 0; k < 4; ++k) {
                    yv[i][0] += pav[k] * xb[k].x;
                    yv[i][1] += pav[k] * xb[k].y;
                    yv[i][2] += pav[k] * xb[k].z;
                    yv[i][3] += pav[k] * xb[k].w;
                }
            }
        }
        float Dp = D_param[h];
#pragma unroll
        for (int i = 0; i < 4; ++i) {
            int t = t0 + i;
            float fct = Dp / dts[t];          // x = XD/dt
            float* yrow = y + (size_t)(bl0 + t) * D_INNER + h * HEAD_DIM;
            float4 xv = *(float4*)&XDs[t][p0];
            float4 o = make_float4(yv[i][0] + fct * xv.x, yv[i][1] + fct * xv.y,
                                   yv[i][2] + fct * xv.z, yv[i][3] + fct * xv.w);
            *(float4*)(yrow + p0) = o;
        }
    }

    {   // Z[p][n] = sum_t XD[t][p] * (w_t * B[t][n])
        float zv[4][4] = {{0.f}};
#pragma unroll
        for (int t4 = 0; t4 < 16; ++t4) {
            float4 xa[4], bb[4];
#pragma unroll
            for (int k = 0; k < 4; ++k) {
                int t = t4 * 4 + k;
                xa[k] = *(float4*)&XDs[t][t0];
                float4 bv = *(float4*)&Bs[t][s0];
                float wt = wh[t];
                bv.x *= wt; bv.y *= wt; bv.z *= wt; bv.w *= wt;
                bb[k] = bv;
            }
#pragma unroll
            for (int k = 0; k < 4; ++k) {
                float xav[4] = {xa[k].x, xa[k].y, xa[k].z, xa[k].w};
#pragma unroll
                for (int i = 0; i < 4; ++i) {
                    zv[i][0] += xav[i] * bb[k].x;
                    zv[i][1] += xav[i] * bb[k].y;
                    zv[i][2] += xav[i] * bb[k].z;
                    zv[i][3] += xav[i] * bb[k].w;
                }
            }
        }
        float* Zr = Zbuf + (((size_t)(b * NHEADS + h) * NCH) + c) * (HEAD_DIM * D_STATE);
#pragma unroll
        for (int i = 0; i < 4; ++i)
            *(float4*)(Zr + (t0 + i) * D_STATE + s0) =
                make_float4(zv[i][0], zv[i][1], zv[i][2], zv[i][3]);
    }
}

// ---------------- SSD pass B ----------------
__global__ __launch_bounds__(256) void ssd_passB(const float* __restrict__ Zbuf,
                                                 const float* __restrict__ Ebuf,
                                                 float* __restrict__ Sbuf) {
    int bh = blockIdx.x;
    int tid = threadIdx.x;
    const float* Zb = Zbuf + (size_t)bh * NCH * 4096;
    float* Sb = Sbuf + (size_t)bh * NCH * 4096;
    const float* Eb = Ebuf + (size_t)bh * NCH * QC;
    float4 S[4];
#pragma unroll
    for (int k = 0; k < 4; ++k) S[k] = make_float4(0.f, 0.f, 0.f, 0.f);
    for (int c = 0; c < NCH; ++c) {
#pragma unroll
        for (int k = 0; k < 4; ++k)
            *(float4*)(Sb + (size_t)c * 4096 + k * 1024 + tid * 4) = S[k];
        float dec = Eb[c * QC + 63];
#pragma unroll
        for (int k = 0; k < 4; ++k) {
            float4 z = *(const float4*)(Zb + (size_t)c * 4096 + k * 1024 + tid * 4);
            S[k].x = dec * S[k].x + z.x;
            S[k].y = dec * S[k].y + z.y;
            S[k].z = dec * S[k].z + z.z;
            S[k].w = dec * S[k].w + z.w;
        }
    }
}

// ---------------- SSD pass C (conv fused for C) ----------------
__global__ __launch_bounds__(256) void ssd_passC(const float* __restrict__ zxbcdt,
                                                 const float* __restrict__ conv_w,
                                                 const float* __restrict__ conv_b,
                                                 const float* __restrict__ Sbuf,
                                                 const float* __restrict__ Ebuf,
                                                 float* __restrict__ y) {
    int blk = blockIdx.x;
    int h = blk & 15;
    int c = (blk >> 4) & 7;
    int b = blk >> 7;
    int tid = threadIdx.x;
    __shared__ float Cs[QC][LP], Sp[HEAD_DIM][LP];
    __shared__ float Eh[QC];
    int bl0 = b * L_SZ + c * QC;
    const float* zb = zxbcdt + (size_t)bl0 * D_IN_PROJ;
    int row16 = tid >> 4, col4 = (tid & 15) * 4;
    const float* Sr = Sbuf + (((size_t)(b * NHEADS + h) * NCH) + c) * 4096;
#pragma unroll
    for (int r = 0; r < 4; ++r) {
        int t = r * 16 + row16;
        int gl = c * QC + t;
        *(float4*)&Cs[t][col4] =
            conv4(zb + (size_t)t * D_IN_PROJ, gl, D_INNER + D_INNER + D_STATE + col4, conv_w, conv_b);
        *(float4*)&Sp[t][col4] = *(const float4*)(Sr + t * 64 + col4);
    }
    if (tid < 64)
        Eh[tid] = Ebuf[(((size_t)(b * NHEADS + h) * NCH) + c) * QC + tid];
    __syncthreads();

    int tx = tid & 15, ty = tid >> 4;
    int t0 = ty * 4, p0 = tx * 4;
    float acc[4][4] = {{0.f}};
#pragma unroll
    for (int n4 = 0; n4 < 16; ++n4) {
        float4 ca[4], sb[4];
#pragma unroll
        for (int i = 0; i < 4; ++i) ca[i] = *(float4*)&Cs[t0 + i][n4 * 4];
#pragma unroll
        for (int j = 0; j < 4; ++j) sb[j] = *(float4*)&Sp[p0 + j][n4 * 4];
#pragma unroll
        for (int i = 0; i < 4; ++i)
#pragma unroll
            for (int j = 0; j < 4; ++j)
                acc[i][j] += ca[i].x * sb[j].x + ca[i].y * sb[j].y +
                             ca[i].z * sb[j].z + ca[i].w * sb[j].w;
    }
#pragma unroll
    for (int i = 0; i < 4; ++i) {
        int t = t0 + i;
        float Et = Eh[t];
        float* yrow = y + (size_t)(bl0 + t) * D_INNER + h * HEAD_DIM;
        float4 old = *(float4*)(yrow + p0);
        old.x += Et * acc[i][0];
        old.y += Et * acc[i][1];
        old.z += Et * acc[i][2];
        old.w += Et * acc[i][3];
        *(float4*)(yrow + p0) = old;
    }
}

// ---------------- gate (SiLU(z)) + RMSNorm -> bf16 ----------------
__global__ __launch_bounds__(256) void gated_rmsnorm_kernel(const float* __restrict__ zxbcdt,
                                                            const float* __restrict__ y,
                                                            const float* __restrict__ rms_w,
                                                            unsigned short* __restrict__ yn_bf) {
    int bl = blockIdx.x;
    int tid = threadIdx.x;
    __shared__ float red[4];
    __shared__ float sscale;
    float vals[4];
    float sumsq = 0.f;
#pragma unroll
    for (int i = 0; i < 4; ++i) {
        int col = tid + i * 256;
        float yv = y[(size_t)bl * D_INNER + col];
        float z = zxbcdt[(size_t)bl * D_IN_PROJ + col];
        float yz = yv * (z / (1.f + expf(-z)));
        vals[i] = yz;
        sumsq += yz * yz;
    }
#pragma unroll
    for (int off = 32; off; off >>= 1) sumsq += __shfl_xor(sumsq, off);
    int wave = tid >> 6, lane = tid & 63;
    if (lane == 0) red[wave] = sumsq;
    __syncthreads();
    if (tid == 0) {
        float t = red[0] + red[1] + red[2] + red[3];
        sscale = rsqrtf(t / (float)D_INNER + RMS_EPS);
    }
    __syncthreads();
    float sc = sscale;
#pragma unroll
    for (int i = 0; i < 4; ++i) {
        int col = tid + i * 256;
        yn_bf[(size_t)bl * D_INNER + col] = f2bf(vals[i] * sc * rms_w[col]);
    }
}

// ---------------- launch ----------------
extern "C" void kernel_launch(void* const* d_in, const int* in_sizes, int n_in,
                              void* d_out, int out_size, void* d_ws, size_t ws_size,
                              hipStream_t stream) {
    const float* u       = (const float*)d_in[0];
    const float* W_in    = (const float*)d_in[1];
    const float* conv_w  = (const float*)d_in[2];
    const float* conv_b  = (const float*)d_in[3];
    const float* dt_bias = (const float*)d_in[4];
    const float* A_log   = (const float*)d_in[5];
    const float* D_param = (const float*)d_in[6];
    const float* rms_w   = (const float*)d_in[7];
    const float* W_out   = (const float*)d_in[8];
    float* out = (float*)d_out;

    float* ws = (float*)d_ws;
    float* zxbcdt = ws;                                    // [1024][2192] f32
    float* y      = zxbcdt + (size_t)BL * D_IN_PROJ;       // [1024][1024] f32
    float* Zbuf   = y + (size_t)BL * D_INNER;              // [32][8][64][64] f32
    float* Sbuf   = Zbuf + (size_t)32 * NCH * 4096;        // [32][8][64][64] f32
    float* Ebuf   = Sbuf + (size_t)32 * NCH * 4096;        // [32][8][64] f32
    unsigned short* u_bf  = (unsigned short*)(Ebuf + 32 * NCH * QC);   // [1024][512]
    unsigned short* Wt1   = u_bf + (size_t)BL * D_MODEL;               // [2304][512]
    unsigned short* Wt2   = Wt1 + (size_t)NPAD1 * D_MODEL;             // [512][1024]
    unsigned short* yn_bf = Wt2 + (size_t)D_MODEL * D_INNER;           // [1024][1024]

    // 0) convert/transpose weights + u to bf16
    prep_kernel<<<672, 256, 0, stream>>>(W_in, W_out, u, Wt1, Wt2, u_bf);

    // 1) in_proj: zxbcdt = u @ W_in
    gemm_mfma64<<<dim3(NPAD1 / 64, BL / 64), 256, 0, stream>>>(
        u_bf, Wt1, zxbcdt, D_IN_PROJ, D_MODEL);

    // 2) SSD (conv fused into passes)
    ssd_passA<<<B_SZ * NCH * NHEADS, 256, 0, stream>>>(
        zxbcdt, conv_w, conv_b, dt_bias, A_log, D_param, y, Zbuf, Ebuf);
    ssd_passB<<<B_SZ * NHEADS, 256, 0, stream>>>(Zbuf, Ebuf, Sbuf);
    ssd_passC<<<B_SZ * NCH * NHEADS, 256, 0, stream>>>(
        zxbcdt, conv_w, conv_b, Sbuf, Ebuf, y);

    // 3) gate + RMSNorm -> bf16
    gated_rmsnorm_kernel<<<BL, 256, 0, stream>>>(zxbcdt, y, rms_w, yn_bf);

    // 4) out_proj: out = yn @ W_out
    gemm_mfma64<<<dim3(D_MODEL / 64, BL / 64), 256, 0, stream>>>(
        yn_bf, Wt2, out, D_MODEL, D_INNER);
}

// Round 6
// 47.459 us; speedup vs baseline: 9.1525x; 1.3410x over previous
//
#include <hip/hip_runtime.h>
#include <hip/hip_bf16.h>

// ---------------- constants ----------------
#define B_SZ 2
#define L_SZ 512
#define D_MODEL 512
#define D_INNER 1024
#define HEAD_DIM 64
#define NHEADS 16
#define D_STATE 64
#define D_CONV 3
#define CONV_DIM 1152            // D_INNER + 2*D_STATE
#define D_IN_PROJ 2192           // 2*D_INNER + 2*D_STATE + NHEADS
#define BL (B_SZ * L_SZ)         // 1024
#define RMS_EPS 1e-5f
#define QC 64                    // SSD chunk length
#define NCH 8                    // chunks per batch (L_SZ/QC)
#define NPAD1 2304               // W_in^T padded rows (36*64)
#define PB 72                    // bf16 LDS pitch (144B rows: frag reads 2-way = free)

typedef __attribute__((ext_vector_type(8))) short short8t;
typedef __attribute__((ext_vector_type(8))) unsigned short ushort8t;
typedef __attribute__((ext_vector_type(4))) unsigned short ushort4t;
typedef __attribute__((ext_vector_type(4))) float f32x4;

__device__ __forceinline__ unsigned short f2bf(float f) {
    unsigned u = __float_as_uint(f);
    u += 0x7fff + ((u >> 16) & 1);          // round-to-nearest-even
    return (unsigned short)(u >> 16);
}
__device__ __forceinline__ float bf2f(unsigned short u) {
    return __uint_as_float(((unsigned)u) << 16);
}

__device__ __forceinline__ void gload_lds16(const void* g, void* lds) {
    __builtin_amdgcn_global_load_lds(
        (const __attribute__((address_space(1))) unsigned int*)g,
        (__attribute__((address_space(3))) unsigned int*)lds, 16, 0, 0);
}

// ---------------- prep: W_in -> Wt1[2304][512] bf16, W_out -> Wt2[512][1024] bf16, u -> bf16
__device__ __forceinline__ void transpose_tile_bf16(const float* __restrict__ src,
                                                    unsigned short* __restrict__ dst,
                                                    int K, int Nin, int tile, int ntn) {
    __shared__ float T[64][65];
    int tid = threadIdx.x;
    int nt = tile % ntn, kt = tile / ntn;
    int n0 = nt * 64, k0 = kt * 64;
#pragma unroll
    for (int rr = 0; rr < 4; ++rr) {
        int k = k0 + (tid >> 4) + rr * 16;
        int nn = (tid & 15) * 4;
#pragma unroll
        for (int q = 0; q < 4; ++q) {
            int n = n0 + nn + q;
            T[(tid >> 4) + rr * 16][nn + q] = (n < Nin) ? src[(size_t)k * Nin + n] : 0.f;
        }
    }
    __syncthreads();
    int nn2 = tid >> 2, kc = tid & 3;
    unsigned short ov[16];
#pragma unroll
    for (int j = 0; j < 16; ++j) ov[j] = f2bf(T[kc * 16 + j][nn2]);
    unsigned short* p = dst + (size_t)(n0 + nn2) * K + k0 + kc * 16;
    *(ushort8t*)p = *(ushort8t*)&ov[0];
    *(ushort8t*)(p + 8) = *(ushort8t*)&ov[8];
}

__global__ __launch_bounds__(256) void prep_kernel(const float* __restrict__ W_in,
                                                   const float* __restrict__ W_out,
                                                   const float* __restrict__ u,
                                                   unsigned short* __restrict__ Wt1,
                                                   unsigned short* __restrict__ Wt2,
                                                   unsigned short* __restrict__ u_bf) {
    int bid = blockIdx.x;
    if (bid < 288) {
        transpose_tile_bf16(W_in, Wt1, D_MODEL, D_IN_PROJ, bid, 36);
    } else if (bid < 416) {
        transpose_tile_bf16(W_out, Wt2, D_INNER, D_MODEL, bid - 288, 8);
    } else {
        int i = ((bid - 416) * 256 + threadIdx.x) * 8;
        float4 v0 = *(const float4*)(u + i);
        float4 v1 = *(const float4*)(u + i + 4);
        unsigned short ov[8] = {f2bf(v0.x), f2bf(v0.y), f2bf(v0.z), f2bf(v0.w),
                                f2bf(v1.x), f2bf(v1.y), f2bf(v1.z), f2bf(v1.w)};
        *(ushort8t*)(u_bf + i) = *(ushort8t*)&ov[0];
    }
}

// ---------------- bf16 MFMA GEMM: C[M,N] = A[M,K] * Bt[N,K]^T (unchanged r4) ----------------
__global__ __launch_bounds__(256) void gemm_mfma64(const unsigned short* __restrict__ A,
                                                   const unsigned short* __restrict__ Bt,
                                                   float* __restrict__ C,
                                                   int N, int K) {
    __shared__ char sm[49152];          // 3 buf x (A:8192 | B:8192)
    int tid = threadIdx.x;
    int w = tid >> 6, l = tid & 63;
    int m0 = blockIdx.y * 64, n0 = blockIdx.x * 64;
    int wm = w >> 1, wn = w & 1;

    f32x4 acc[2][2];
#pragma unroll
    for (int i = 0; i < 2; ++i)
#pragma unroll
        for (int j = 0; j < 2; ++j) acc[i][j] = (f32x4){0.f, 0.f, 0.f, 0.f};

    auto stage = [&](const unsigned short* src, int row0, int k0, char* dst) {
#pragma unroll
        for (int p = 0; p < 2; ++p) {
            int c = w * 2 + p;
            int row = c * 8 + (l >> 3);
            int scb = ((l & 7) << 4) ^ ((row & 7) << 4);
            gload_lds16(src + (size_t)(row0 + row) * K + k0 + (scb >> 1), dst + c * 1024);
        }
    };

    int nkt = K / 64;
    stage(A, m0, 0, sm);
    stage(Bt, n0, 0, sm + 8192);
    if (nkt > 1) {
        stage(A, m0, 64, sm + 16384);
        stage(Bt, n0, 64, sm + 16384 + 8192);
    }

    for (int kt = 0; kt < nkt; ++kt) {
        if (kt + 2 < nkt) {
            char* d = sm + ((kt + 2) % 3) * 16384;
            stage(A, m0, (kt + 2) * 64, d);
            stage(Bt, n0, (kt + 2) * 64, d + 8192);
        }
        int inflight = nkt - 1 - kt;
        if (inflight >= 2)      asm volatile("s_waitcnt vmcnt(8)" ::: "memory");
        else if (inflight == 1) asm volatile("s_waitcnt vmcnt(4)" ::: "memory");
        else                    asm volatile("s_waitcnt vmcnt(0)" ::: "memory");
        __builtin_amdgcn_s_barrier();

        const char* Ab = sm + (kt % 3) * 16384;
        const char* Bb = Ab + 8192;
#pragma unroll
        for (int kk = 0; kk < 2; ++kk) {
            short8t af[2], bf[2];
#pragma unroll
            for (int i = 0; i < 2; ++i) {
                int r = wm * 32 + i * 16 + (l & 15);
                int cb = (kk * 64 + (l >> 4) * 16) ^ ((r & 7) << 4);
                af[i] = *(const short8t*)(Ab + r * 128 + cb);
            }
#pragma unroll
            for (int j = 0; j < 2; ++j) {
                int r = wn * 32 + j * 16 + (l & 15);
                int cb = (kk * 64 + (l >> 4) * 16) ^ ((r & 7) << 4);
                bf[j] = *(const short8t*)(Bb + r * 128 + cb);
            }
#pragma unroll
            for (int i = 0; i < 2; ++i)
#pragma unroll
                for (int j = 0; j < 2; ++j)
                    acc[i][j] = __builtin_amdgcn_mfma_f32_16x16x32_bf16(af[i], bf[j], acc[i][j], 0, 0, 0);
        }
        __builtin_amdgcn_s_barrier();
    }

#pragma unroll
    for (int i = 0; i < 2; ++i)
#pragma unroll
        for (int j = 0; j < 2; ++j) {
            int row = m0 + wm * 32 + i * 16 + (l >> 4) * 4;
            int col = n0 + wn * 32 + j * 16 + (l & 15);
            if (col < N) {
#pragma unroll
                for (int r = 0; r < 4; ++r)
                    C[(size_t)(row + r) * N + col] = acc[i][j][r];
            }
        }
}

// conv+SiLU of 4 consecutive channels at one row; gl = seq position (causal clamp)
__device__ __forceinline__ float4 conv4(const float* __restrict__ prow, int gl, int zxcol,
                                        const float* __restrict__ conv_w,
                                        const float* __restrict__ conv_b) {
    float4 v2 = *(const float4*)(prow + zxcol);
    float4 v1 = make_float4(0.f, 0.f, 0.f, 0.f), v0 = v1;
    if (gl >= 1) v1 = *(const float4*)(prow - D_IN_PROJ + zxcol);
    if (gl >= 2) v0 = *(const float4*)(prow - 2 * D_IN_PROJ + zxcol);
    int ch = zxcol - D_INNER;
    float4 o;
    float a;
    a = conv_b[ch+0] + conv_w[(ch+0)*3]*v0.x + conv_w[(ch+0)*3+1]*v1.x + conv_w[(ch+0)*3+2]*v2.x;
    o.x = a / (1.f + __expf(-a));
    a = conv_b[ch+1] + conv_w[(ch+1)*3]*v0.y + conv_w[(ch+1)*3+1]*v1.y + conv_w[(ch+1)*3+2]*v2.y;
    o.y = a / (1.f + __expf(-a));
    a = conv_b[ch+2] + conv_w[(ch+2)*3]*v0.z + conv_w[(ch+2)*3+1]*v1.z + conv_w[(ch+2)*3+2]*v2.z;
    o.z = a / (1.f + __expf(-a));
    a = conv_b[ch+3] + conv_w[(ch+3)*3]*v0.w + conv_w[(ch+3)*3+1]*v1.w + conv_w[(ch+3)*3+2]*v2.w;
    o.w = a / (1.f + __expf(-a));
    return o;
}

// ---------------- SSD pass A (conv fused, MFMA matmuls) ----------------
// per (b,c,h): G = C·B^T (MFMA), P = mask(G)·L, Y = P·XD (MFMA) + D·x,
// Z = (w·XD)^T·B (MFMA). Operands staged bf16 in LDS pitch-72.
__global__ __launch_bounds__(256) void ssd_passA(const float* __restrict__ zxbcdt,
                                                 const float* __restrict__ conv_w,
                                                 const float* __restrict__ conv_b,
                                                 const float* __restrict__ dt_bias,
                                                 const float* __restrict__ A_log,
                                                 const float* __restrict__ D_param,
                                                 float* __restrict__ y,
                                                 float* __restrict__ Zbuf,
                                                 float* __restrict__ Ebuf) {
    int blk = blockIdx.x;          // b*128 + c*16 + h
    int h = blk & 15;
    int c = (blk >> 4) & 7;
    int b = blk >> 7;
    int tid = threadIdx.x;

    __shared__ __align__(16) unsigned short Cs_bf[QC][PB];   // C[t][n]
    __shared__ __align__(16) unsigned short Bs_bf[QC][PB];   // B[s][n]
    __shared__ __align__(16) unsigned short BT_bf[QC][PB];   // B^T[n][t]
    __shared__ __align__(16) unsigned short XDT_bf[QC][PB];  // XD^T[p][t]
    __shared__ __align__(16) unsigned short XDTw_bf[QC][PB]; // (w·XD)^T[p][t]
    __shared__ __align__(16) unsigned short P_bf[QC][PB];    // P[t][s]
    __shared__ float csh[QC], dts[QC], wh[QC];

    int bl0 = b * L_SZ + c * QC;
    const float* zb = zxbcdt + (size_t)bl0 * D_IN_PROJ;

    // --- phase 1a: dt, cumsum, decays (wave 0) ---
    if (tid < 64) {
        int t = tid;
        float draw = zb[(size_t)t * D_IN_PROJ + 2 * D_INNER + 2 * D_STATE + h];
        float dtv = draw + dt_bias[h];
        dtv = (dtv > 20.f) ? dtv : log1pf(expf(dtv));
        float A = -expf(A_log[h]);
        float cs = A * dtv;
#pragma unroll
        for (int off = 1; off < 64; off <<= 1) {
            float tmp = __shfl_up(cs, off);
            if (t >= off) cs += tmp;
        }
        float cs63 = __shfl(cs, 63);
        dts[t] = dtv;
        csh[t] = cs;
        wh[t] = __expf(cs63 - cs);
        Ebuf[(((size_t)(b * NHEADS + h) * NCH) + c) * QC + t] = __expf(cs);
    }

    int row16 = tid >> 4;          // 0..15
    int col4 = (tid & 15) * 4;     // 0..60
    // --- phase 1b: conv B, C -> bf16 (+ transposed B) ---
#pragma unroll
    for (int r = 0; r < 4; ++r) {
        int t = r * 16 + row16;
        int gl = c * QC + t;
        const float* prow = zb + (size_t)t * D_IN_PROJ;
        float4 Bv = conv4(prow, gl, D_INNER + D_INNER + col4, conv_w, conv_b);
        float4 Cv = conv4(prow, gl, D_INNER + D_INNER + D_STATE + col4, conv_w, conv_b);
        ushort4t bq = {f2bf(Bv.x), f2bf(Bv.y), f2bf(Bv.z), f2bf(Bv.w)};
        ushort4t cq = {f2bf(Cv.x), f2bf(Cv.y), f2bf(Cv.z), f2bf(Cv.w)};
        *(ushort4t*)&Bs_bf[t][col4] = bq;
        *(ushort4t*)&Cs_bf[t][col4] = cq;
#pragma unroll
        for (int q = 0; q < 4; ++q) BT_bf[col4 + q][t] = bq[q];
    }
    __syncthreads();

    // --- phase 2a: XD (x*dt) -> transposed bf16 (plain + w-scaled) ---
#pragma unroll
    for (int r = 0; r < 4; ++r) {
        int t = r * 16 + row16;
        int gl = c * QC + t;
        const float* prow = zb + (size_t)t * D_IN_PROJ;
        float4 xv = conv4(prow, gl, D_INNER + h * HEAD_DIM + col4, conv_w, conv_b);
        float d = dts[t], wt = wh[t];
        xv.x *= d; xv.y *= d; xv.z *= d; xv.w *= d;
        ushort4t xq = {f2bf(xv.x), f2bf(xv.y), f2bf(xv.z), f2bf(xv.w)};
        ushort4t xwq = {f2bf(xv.x * wt), f2bf(xv.y * wt), f2bf(xv.z * wt), f2bf(xv.w * wt)};
#pragma unroll
        for (int q = 0; q < 4; ++q) {
            XDT_bf[col4 + q][t] = xq[q];
            XDTw_bf[col4 + q][t] = xwq[q];
        }
    }

    int l = tid & 63, wv = tid >> 6;
    int wm = wv >> 1, wn = wv & 1;     // 2x2 waves over 64x64
    int fr = l & 15, fq = l >> 4;      // frag row(lane) / k-block

    // --- phase 2b: G = C·B^T via MFMA, then mask+decay -> P_bf ---
    {
        f32x4 g[2][2];
#pragma unroll
        for (int i = 0; i < 2; ++i)
#pragma unroll
            for (int j = 0; j < 2; ++j) g[i][j] = (f32x4){0.f, 0.f, 0.f, 0.f};
#pragma unroll
        for (int kk = 0; kk < 2; ++kk) {
            short8t af[2], bb[2];
#pragma unroll
            for (int i = 0; i < 2; ++i)
                af[i] = *(const short8t*)&Cs_bf[wm * 32 + i * 16 + fr][kk * 32 + fq * 8];
#pragma unroll
            for (int j = 0; j < 2; ++j)
                bb[j] = *(const short8t*)&Bs_bf[wn * 32 + j * 16 + fr][kk * 32 + fq * 8];
#pragma unroll
            for (int i = 0; i < 2; ++i)
#pragma unroll
                for (int j = 0; j < 2; ++j)
                    g[i][j] = __builtin_amdgcn_mfma_f32_16x16x32_bf16(af[i], bb[j], g[i][j], 0, 0, 0);
        }
#pragma unroll
        for (int i = 0; i < 2; ++i)
#pragma unroll
            for (int j = 0; j < 2; ++j) {
                int s = wn * 32 + j * 16 + fr;
                float css = csh[s];
#pragma unroll
                for (int r = 0; r < 4; ++r) {
                    int t = wm * 32 + i * 16 + fq * 4 + r;
                    float v = (s <= t) ? g[i][j][r] * __expf(csh[t] - css) : 0.f;
                    P_bf[t][s] = f2bf(v);
                }
            }
    }
    __syncthreads();

    // --- phase 3a: Y = P·XD via MFMA; epilogue + D·x ---
    {
        f32x4 yv[2][2];
#pragma unroll
        for (int i = 0; i < 2; ++i)
#pragma unroll
            for (int j = 0; j < 2; ++j) yv[i][j] = (f32x4){0.f, 0.f, 0.f, 0.f};
#pragma unroll
        for (int kk = 0; kk < 2; ++kk) {
            short8t af[2], bb[2];
#pragma unroll
            for (int i = 0; i < 2; ++i)
                af[i] = *(const short8t*)&P_bf[wm * 32 + i * 16 + fr][kk * 32 + fq * 8];
#pragma unroll
            for (int j = 0; j < 2; ++j)
                bb[j] = *(const short8t*)&XDT_bf[wn * 32 + j * 16 + fr][kk * 32 + fq * 8];
#pragma unroll
            for (int i = 0; i < 2; ++i)
#pragma unroll
                for (int j = 0; j < 2; ++j)
                    yv[i][j] = __builtin_amdgcn_mfma_f32_16x16x32_bf16(af[i], bb[j], yv[i][j], 0, 0, 0);
        }
        float Dp = D_param[h];
#pragma unroll
        for (int i = 0; i < 2; ++i)
#pragma unroll
            for (int j = 0; j < 2; ++j) {
                int p = wn * 32 + j * 16 + fr;
#pragma unroll
                for (int r = 0; r < 4; ++r) {
                    int t = wm * 32 + i * 16 + fq * 4 + r;
                    float xval = bf2f(XDT_bf[p][t]);       // XD[t][p]
                    float fct = Dp / dts[t];               // x = XD/dt
                    y[(size_t)(bl0 + t) * D_INNER + h * HEAD_DIM + p] =
                        yv[i][j][r] + fct * xval;
                }
            }
    }

    // --- phase 3b: Z = (w·XD)^T·B via MFMA -> Zbuf ---
    {
        f32x4 zv[2][2];
#pragma unroll
        for (int i = 0; i < 2; ++i)
#pragma unroll
            for (int j = 0; j < 2; ++j) zv[i][j] = (f32x4){0.f, 0.f, 0.f, 0.f};
#pragma unroll
        for (int kk = 0; kk < 2; ++kk) {
            short8t af[2], bb[2];
#pragma unroll
            for (int i = 0; i < 2; ++i)
                af[i] = *(const short8t*)&XDTw_bf[wm * 32 + i * 16 + fr][kk * 32 + fq * 8];
#pragma unroll
            for (int j = 0; j < 2; ++j)
                bb[j] = *(const short8t*)&BT_bf[wn * 32 + j * 16 + fr][kk * 32 + fq * 8];
#pragma unroll
            for (int i = 0; i < 2; ++i)
#pragma unroll
                for (int j = 0; j < 2; ++j)
                    zv[i][j] = __builtin_amdgcn_mfma_f32_16x16x32_bf16(af[i], bb[j], zv[i][j], 0, 0, 0);
        }
        float* Zr = Zbuf + (((size_t)(b * NHEADS + h) * NCH) + c) * (HEAD_DIM * D_STATE);
#pragma unroll
        for (int i = 0; i < 2; ++i)
#pragma unroll
            for (int j = 0; j < 2; ++j) {
                int n = wn * 32 + j * 16 + fr;
#pragma unroll
                for (int r = 0; r < 4; ++r) {
                    int p = wm * 32 + i * 16 + fq * 4 + r;
                    Zr[p * D_STATE + n] = zv[i][j][r];
                }
            }
    }
}

// ---------------- SSD pass C (passB folded: per-block chunk-state sum; MFMA) ----------------
__global__ __launch_bounds__(256) void ssd_passC(const float* __restrict__ zxbcdt,
                                                 const float* __restrict__ conv_w,
                                                 const float* __restrict__ conv_b,
                                                 const float* __restrict__ Zbuf,
                                                 const float* __restrict__ Ebuf,
                                                 float* __restrict__ y) {
    int blk = blockIdx.x;          // b*128 + c*16 + h
    int h = blk & 15;
    int c = (blk >> 4) & 7;
    int b = blk >> 7;
    if (c == 0) return;            // Y_off(chunk 0) = 0
    int tid = threadIdx.x;

    __shared__ __align__(16) unsigned short Cs_bf[QC][PB];   // C[t][n]
    __shared__ __align__(16) unsigned short S_bf[QC][PB];    // S_prev[p][n]
    __shared__ float Eh[QC];

    int bl0 = b * L_SZ + c * QC;
    const float* zb = zxbcdt + (size_t)bl0 * D_IN_PROJ;
    const float* Zb = Zbuf + ((size_t)(b * NHEADS + h) * NCH) * (HEAD_DIM * D_STATE);
    const float* Eb = Ebuf + ((size_t)(b * NHEADS + h) * NCH) * QC;

    // S_prev(c) = sum_{j<c} (prod_{m=j+1}^{c-1} dec_m) Z(j)   (thread: p=tid>>2, 16 n's)
    {
        int p = tid >> 2, nq = (tid & 3) * 16;
        float S16[16];
#pragma unroll
        for (int q = 0; q < 16; ++q) S16[q] = 0.f;
        float wgt = 1.f;
        for (int j = c - 1; j >= 0; --j) {
            const float* Zj = Zb + (size_t)j * (HEAD_DIM * D_STATE) + p * D_STATE + nq;
#pragma unroll
            for (int q4 = 0; q4 < 4; ++q4) {
                float4 z = *(const float4*)(Zj + q4 * 4);
                S16[q4 * 4 + 0] += wgt * z.x;
                S16[q4 * 4 + 1] += wgt * z.y;
                S16[q4 * 4 + 2] += wgt * z.z;
                S16[q4 * 4 + 3] += wgt * z.w;
            }
            wgt *= Eb[(size_t)j * QC + 63];
        }
#pragma unroll
        for (int q4 = 0; q4 < 4; ++q4) {
            ushort4t s4 = {f2bf(S16[q4 * 4 + 0]), f2bf(S16[q4 * 4 + 1]),
                           f2bf(S16[q4 * 4 + 2]), f2bf(S16[q4 * 4 + 3])};
            *(ushort4t*)&S_bf[p][nq + q4 * 4] = s4;
        }
    }

    // conv C -> bf16
    int row16 = tid >> 4, col4 = (tid & 15) * 4;
#pragma unroll
    for (int r = 0; r < 4; ++r) {
        int t = r * 16 + row16;
        int gl = c * QC + t;
        float4 Cv = conv4(zb + (size_t)t * D_IN_PROJ, gl,
                          D_INNER + D_INNER + D_STATE + col4, conv_w, conv_b);
        ushort4t cq = {f2bf(Cv.x), f2bf(Cv.y), f2bf(Cv.z), f2bf(Cv.w)};
        *(ushort4t*)&Cs_bf[t][col4] = cq;
    }
    if (tid < 64)
        Eh[tid] = Ebuf[(((size_t)(b * NHEADS + h) * NCH) + c) * QC + tid];
    __syncthreads();

    // Y_off = E ∘ (C·S^T) via MFMA; accumulate into y
    int l = tid & 63, wv = tid >> 6;
    int wm = wv >> 1, wn = wv & 1;
    int fr = l & 15, fq = l >> 4;
    f32x4 acc[2][2];
#pragma unroll
    for (int i = 0; i < 2; ++i)
#pragma unroll
        for (int j = 0; j < 2; ++j) acc[i][j] = (f32x4){0.f, 0.f, 0.f, 0.f};
#pragma unroll
    for (int kk = 0; kk < 2; ++kk) {
        short8t af[2], bb[2];
#pragma unroll
        for (int i = 0; i < 2; ++i)
            af[i] = *(const short8t*)&Cs_bf[wm * 32 + i * 16 + fr][kk * 32 + fq * 8];
#pragma unroll
        for (int j = 0; j < 2; ++j)
            bb[j] = *(const short8t*)&S_bf[wn * 32 + j * 16 + fr][kk * 32 + fq * 8];
#pragma unroll
        for (int i = 0; i < 2; ++i)
#pragma unroll
            for (int j = 0; j < 2; ++j)
                acc[i][j] = __builtin_amdgcn_mfma_f32_16x16x32_bf16(af[i], bb[j], acc[i][j], 0, 0, 0);
    }
#pragma unroll
    for (int i = 0; i < 2; ++i)
#pragma unroll
        for (int j = 0; j < 2; ++j) {
            int p = wn * 32 + j * 16 + fr;
#pragma unroll
            for (int r = 0; r < 4; ++r) {
                int t = wm * 32 + i * 16 + fq * 4 + r;
                float* yp = y + (size_t)(bl0 + t) * D_INNER + h * HEAD_DIM + p;
                *yp += Eh[t] * acc[i][j][r];
            }
        }
}

// ---------------- gate (SiLU(z)) + RMSNorm -> bf16 ----------------
__global__ __launch_bounds__(256) void gated_rmsnorm_kernel(const float* __restrict__ zxbcdt,
                                                            const float* __restrict__ y,
                                                            const float* __restrict__ rms_w,
                                                            unsigned short* __restrict__ yn_bf) {
    int bl = blockIdx.x;
    int tid = threadIdx.x;
    __shared__ float red[4];
    __shared__ float sscale;
    float vals[4];
    float sumsq = 0.f;
#pragma unroll
    for (int i = 0; i < 4; ++i) {
        int col = tid + i * 256;
        float yv = y[(size_t)bl * D_INNER + col];
        float z = zxbcdt[(size_t)bl * D_IN_PROJ + col];
        float yz = yv * (z / (1.f + expf(-z)));
        vals[i] = yz;
        sumsq += yz * yz;
    }
#pragma unroll
    for (int off = 32; off; off >>= 1) sumsq += __shfl_xor(sumsq, off);
    int wave = tid >> 6, lane = tid & 63;
    if (lane == 0) red[wave] = sumsq;
    __syncthreads();
    if (tid == 0) {
        float t = red[0] + red[1] + red[2] + red[3];
        sscale = rsqrtf(t / (float)D_INNER + RMS_EPS);
    }
    __syncthreads();
    float sc = sscale;
#pragma unroll
    for (int i = 0; i < 4; ++i) {
        int col = tid + i * 256;
        yn_bf[(size_t)bl * D_INNER + col] = f2bf(vals[i] * sc * rms_w[col]);
    }
}

// ---------------- launch ----------------
extern "C" void kernel_launch(void* const* d_in, const int* in_sizes, int n_in,
                              void* d_out, int out_size, void* d_ws, size_t ws_size,
                              hipStream_t stream) {
    const float* u       = (const float*)d_in[0];
    const float* W_in    = (const float*)d_in[1];
    const float* conv_w  = (const float*)d_in[2];
    const float* conv_b  = (const float*)d_in[3];
    const float* dt_bias = (const float*)d_in[4];
    const float* A_log   = (const float*)d_in[5];
    const float* D_param = (const float*)d_in[6];
    const float* rms_w   = (const float*)d_in[7];
    const float* W_out   = (const float*)d_in[8];
    float* out = (float*)d_out;

    float* ws = (float*)d_ws;
    float* zxbcdt = ws;                                    // [1024][2192] f32
    float* y      = zxbcdt + (size_t)BL * D_IN_PROJ;       // [1024][1024] f32
    float* Zbuf   = y + (size_t)BL * D_INNER;              // [32][8][64][64] f32
    float* Ebuf   = Zbuf + (size_t)32 * NCH * 4096;        // [32][8][64] f32
    unsigned short* u_bf  = (unsigned short*)(Ebuf + 32 * NCH * QC);   // [1024][512]
    unsigned short* Wt1   = u_bf + (size_t)BL * D_MODEL;               // [2304][512]
    unsigned short* Wt2   = Wt1 + (size_t)NPAD1 * D_MODEL;             // [512][1024]
    unsigned short* yn_bf = Wt2 + (size_t)D_MODEL * D_INNER;           // [1024][1024]

    // 0) convert/transpose weights + u to bf16
    prep_kernel<<<672, 256, 0, stream>>>(W_in, W_out, u, Wt1, Wt2, u_bf);

    // 1) in_proj: zxbcdt = u @ W_in
    gemm_mfma64<<<dim3(NPAD1 / 64, BL / 64), 256, 0, stream>>>(
        u_bf, Wt1, zxbcdt, D_IN_PROJ, D_MODEL);

    // 2) SSD (conv fused; MFMA matmuls; passB folded into passC)
    ssd_passA<<<B_SZ * NCH * NHEADS, 256, 0, stream>>>(
        zxbcdt, conv_w, conv_b, dt_bias, A_log, D_param, y, Zbuf, Ebuf);
    ssd_passC<<<B_SZ * NCH * NHEADS, 256, 0, stream>>>(
        zxbcdt, conv_w, conv_b, Zbuf, Ebuf, y);

    // 3) gate + RMSNorm -> bf16
    gated_rmsnorm_kernel<<<BL, 256, 0, stream>>>(zxbcdt, y, rms_w, yn_bf);

    // 4) out_proj: out = yn @ W_out
    gemm_mfma64<<<dim3(D_MODEL / 64, BL / 64), 256, 0, stream>>>(
        yn_bf, Wt2, out, D_MODEL, D_INNER);
}